// Round 1
// 678.813 us; speedup vs baseline: 1.1080x; 1.1080x over previous
//
#include <hip/hip_runtime.h>
#include <math.h>

#define D_MODEL 1024
#define D_STATE 32
#define D_CONV  4
#define D_INNER 2048
#define DT_RANK 64
#define BATCH   4
#define SEQ     2048
#define NTOK    (BATCH*SEQ)            // 8192 rows
#define DBC_N   (DT_RANK + 2*D_STATE)  // 128
#define NC      64                     // scan chunks
#define CL      (SEQ/NC)               // 32 steps per chunk
#define KSPLIT  8                      // split-K factor for dbc GEMM
#define LOG2E   1.4426950408889634f

typedef unsigned short u16;
typedef short bf16x8 __attribute__((ext_vector_type(8)));
typedef float f32x4  __attribute__((ext_vector_type(4)));

__device__ __forceinline__ float bf2f(u16 u){
  return __uint_as_float(((unsigned)u) << 16);
}
__device__ __forceinline__ u16 f2bf(float f){   // round-to-nearest-even
  unsigned u = __float_as_uint(f);
  return (u16)((u + 0x7fffu + ((u >> 16) & 1u)) >> 16);
}
__device__ __forceinline__ float sigmoidf_(float x){ return 1.f/(1.f+__expf(-x)); }
// raw v_exp_f32: r = 2^x (1 instruction; __expf = mul + this)
__device__ __forceinline__ float exp2_fast(float x){
  float r;
  asm("v_exp_f32 %0, %1" : "=v"(r) : "v"(x));
  return r;
}

typedef __attribute__((address_space(3))) void       lds_v;
typedef const __attribute__((address_space(1))) void gl_v;
#define GLOAD_LDS16(g, l) \
  __builtin_amdgcn_global_load_lds((gl_v*)(g), (lds_v*)(l), 16, 0, 0)

// ---------------------------------------------------------------------------
// bf16 MFMA GEMM: C = A[M,K] @ W[K,N], A bf16 row-major [M][K], B = weight
// PRE-TRANSPOSED bf16 [N][K]. 128x128 tile, BK=32, 4 waves of 64x64.
// Staging via global_load_lds width=16 into LINEAR [128][32] LDS (m97
// structure: lane l of wave w lands at bytes w*1024 + l*16 -> row tid/4,
// elem (tid%4)*8; global src pre-offset to match).
// MODE 0: f32 store. MODE 2 (split in_proj): col<D_INNER -> f32 C1;
// col>=D_INNER -> bf16 C2@col-2048.
// ---------------------------------------------------------------------------
template<int MODE>
__global__ __launch_bounds__(256)
void mfma_gemm(int K,
               const u16* __restrict__ A, int lda,
               const u16* __restrict__ B, int ldb,   // [N][K]
               void* __restrict__ C1, int ldc,
               u16*  __restrict__ C2)
{
  __shared__ u16 As[128*32];
  __shared__ u16 Bs[128*32];
  const int tid  = threadIdx.x;
  const int lane = tid & 63;
  const int wave = tid >> 6;
  const int wm = (wave>>1)*64, wn = (wave&1)*64;
  const int m0 = blockIdx.y*128, n0 = blockIdx.x*128;

  const int srow = tid >> 2;        // 0..63 (row within 64-row half-tile)
  const int sc8  = (tid & 3) * 8;   // elem offset within 32-wide K slice

  const u16* Ag = A + (size_t)(m0 + srow)*lda + sc8;
  const u16* Bg = B + (size_t)(n0 + srow)*ldb + sc8;

  const int fr = lane & 15;         // fragment row within 16
  const int fq = lane >> 4;         // quad: k-chunk of 8
  f32x4 acc[4][4] = {};

  u16* as0 = &As[tid*8];
  u16* as1 = &As[2048 + tid*8];
  u16* bs0 = &Bs[tid*8];
  u16* bs1 = &Bs[2048 + tid*8];

  for (int k0=0; k0<K; k0+=32){
    GLOAD_LDS16(Ag + k0,                    as0);
    GLOAD_LDS16(Ag + (size_t)64*lda + k0,   as1);
    GLOAD_LDS16(Bg + k0,                    bs0);
    GLOAD_LDS16(Bg + (size_t)64*ldb + k0,   bs1);
    __syncthreads();                 // drains vmcnt -> LDS tile ready

    bf16x8 af[4], bfr[4];
    #pragma unroll
    for (int i=0;i<4;i++){
      af[i]  = *(const bf16x8*)&As[(wm + i*16 + fr)*32 + fq*8];
      bfr[i] = *(const bf16x8*)&Bs[(wn + i*16 + fr)*32 + fq*8];
    }
    #pragma unroll
    for (int mi=0;mi<4;mi++)
      #pragma unroll
      for (int ni=0;ni<4;ni++)
        acc[mi][ni] = __builtin_amdgcn_mfma_f32_16x16x32_bf16(
            af[mi], bfr[ni], acc[mi][ni], 0, 0, 0);
    __syncthreads();                 // all reads done before next overwrite
  }

  // C/D layout: row = fq*4 + r, col = fr  (m89-verified)
  const bool second = (MODE==2) && (n0 >= D_INNER);   // block-uniform
  #pragma unroll
  for (int mi=0;mi<4;mi++){
    #pragma unroll
    for (int ni=0;ni<4;ni++){
      int col = n0 + wn + ni*16 + fr;
      #pragma unroll
      for (int r=0;r<4;r++){
        int row = m0 + wm + mi*16 + fq*4 + r;
        float v = acc[mi][ni][r];
        if (MODE==0)      ((float*)C1)[(size_t)row*ldc + col] = v;
        else {
          if (second) C2[(size_t)row*D_INNER + (col - D_INNER)] = f2bf(v);
          else        ((float*)C1)[(size_t)row*D_INNER + col] = v;
        }
      }
    }
  }
}

// ---------------------------------------------------------------------------
// f32 -> bf16 elementwise (n multiple of 1024)
// ---------------------------------------------------------------------------
__global__ __launch_bounds__(256)
void cvt_f32_bf16(const float* __restrict__ in, u16* __restrict__ out)
{
  size_t i = (size_t)blockIdx.x*256 + threadIdx.x;
  float4 v = ((const float4*)in)[i];
  ushort4 o;
  o.x=f2bf(v.x); o.y=f2bf(v.y); o.z=f2bf(v.z); o.w=f2bf(v.w);
  ((ushort4*)out)[i] = o;
}

// ---------------------------------------------------------------------------
// f32 [R][C] -> bf16 [C][R] transpose+convert, 64x64 tiles, 256 threads.
// ---------------------------------------------------------------------------
__global__ __launch_bounds__(256)
void transpose_cvt(const float* __restrict__ in, u16* __restrict__ out,
                   int R, int C)
{
  __shared__ float tile[64][65];
  const int bc = blockIdx.x*64, br = blockIdx.y*64;
  const int tx = threadIdx.x & 63, ty = threadIdx.x >> 6;
  #pragma unroll
  for (int i=0;i<16;i++){
    int r = ty + i*4;
    tile[r][tx] = in[(size_t)(br+r)*C + bc+tx];
  }
  __syncthreads();
  #pragma unroll
  for (int i=0;i<16;i++){
    int r = ty + i*4;
    out[(size_t)(bc+r)*R + br+tx] = f2bf(tile[tx][r]);
  }
}

// ---------------------------------------------------------------------------
// f32 tiled GEMM: C[M,N] = A[M,K] @ B[K,N]
// EPI: 0 plain, 1 softplus(acc + bias[col]).
// ---------------------------------------------------------------------------
template<int BM,int BN,int BK,int TM,int TN,int EPI>
__global__ __launch_bounds__((BM/TM)*(BN/TN))
void sgemm(int K,
           const float* __restrict__ A,int lda,
           const float* __restrict__ B,int ldb,
           float* __restrict__ C,int ldc,
           const float* __restrict__ bias)
{
  __shared__ float As[BK][BM];
  __shared__ float Bs[BK][BN];
  const int tid  = threadIdx.x;
  const int brow = blockIdx.y, bcol = blockIdx.x;
  const int tcol = tid % (BN/TN);
  const int trow = tid / (BN/TN);

  const float* Ag = A + (size_t)brow*BM*lda;
  const float* Bg = B + (size_t)bcol*BN;

  const int arow = tid / (BK/4);
  const int acol = (tid % (BK/4))*4;
  const int brw  = tid / (BN/4);
  const int bcv  = (tid % (BN/4))*4;

  float acc[TM][TN] = {};

  for (int k0=0; k0<K; k0+=BK){
    float4 av = *(const float4*)(Ag + (size_t)arow*lda + k0 + acol);
    float4 bv = *(const float4*)(Bg + (size_t)(k0+brw)*ldb + bcv);
    __syncthreads();
    As[acol+0][arow]=av.x; As[acol+1][arow]=av.y;
    As[acol+2][arow]=av.z; As[acol+3][arow]=av.w;
    *(float4*)&Bs[brw][bcv] = bv;
    __syncthreads();
    #pragma unroll
    for (int kk=0;kk<BK;kk++){
      float ra[TM], rb[TN];
      #pragma unroll
      for (int m=0;m<TM;m++) ra[m]=As[kk][trow*TM+m];
      #pragma unroll
      for (int n=0;n<TN;n++) rb[n]=Bs[kk][tcol*TN+n];
      #pragma unroll
      for (int m=0;m<TM;m++)
        #pragma unroll
        for (int n=0;n<TN;n++)
          acc[m][n] += ra[m]*rb[n];
    }
  }

  #pragma unroll
  for (int m=0;m<TM;m++){
    int row = brow*BM + trow*TM + m;
    #pragma unroll
    for (int n=0;n<TN;n++){
      int col = bcol*BN + tcol*TN + n;
      float v = acc[m][n];
      if (EPI==1){
        v += bias[col];
        v = (v > 20.f) ? v : log1pf(__expf(v));
      }
      C[(size_t)row*ldc + col] = v;
    }
  }
}

// ---------------------------------------------------------------------------
// Split-K f32 GEMM (dbc): partial[z] = A[:, zKc:(z+1)Kc] @ B[zKc:, :]
// 64x64 tile, BK=16. grid = (N/64, M/64, KSPLIT). Kc = K/KSPLIT.
// ---------------------------------------------------------------------------
__global__ __launch_bounds__(256)
void sgemm_pk(int K,
              const float* __restrict__ A,int lda,
              const float* __restrict__ B,int ldb,
              float* __restrict__ part)          // (KSPLIT, NTOK, DBC_N)
{
  const int BM=64, BN=64, BK=16, TM=4, TN=4;
  __shared__ float As[BK][BM];
  __shared__ float Bs[BK][BN];
  const int tid  = threadIdx.x;
  const int brow = blockIdx.y, bcol = blockIdx.x, kz = blockIdx.z;
  const int Kc   = K / KSPLIT;
  const int tcol = tid % (BN/TN);
  const int trow = tid / (BN/TN);

  const float* Ag = A + (size_t)brow*BM*lda + (size_t)kz*Kc;
  const float* Bg = B + (size_t)kz*Kc*ldb + (size_t)bcol*BN;

  const int arow = tid / (BK/4);
  const int acol = (tid % (BK/4))*4;
  const int brw  = tid / (BN/4);
  const int bcv  = (tid % (BN/4))*4;

  float acc[TM][TN] = {};

  for (int k0=0; k0<Kc; k0+=BK){
    float4 av = *(const float4*)(Ag + (size_t)arow*lda + k0 + acol);
    float4 bv = *(const float4*)(Bg + (size_t)(k0+brw)*ldb + bcv);
    __syncthreads();
    As[acol+0][arow]=av.x; As[acol+1][arow]=av.y;
    As[acol+2][arow]=av.z; As[acol+3][arow]=av.w;
    *(float4*)&Bs[brw][bcv] = bv;
    __syncthreads();
    #pragma unroll
    for (int kk=0;kk<BK;kk++){
      float ra[TM], rb[TN];
      #pragma unroll
      for (int m=0;m<TM;m++) ra[m]=As[kk][trow*TM+m];
      #pragma unroll
      for (int n=0;n<TN;n++) rb[n]=Bs[kk][tcol*TN+n];
      #pragma unroll
      for (int m=0;m<TM;m++)
        #pragma unroll
        for (int n=0;n<TN;n++)
          acc[m][n] += ra[m]*rb[n];
    }
  }

  float* P = part + (size_t)kz*NTOK*DBC_N;
  #pragma unroll
  for (int m=0;m<TM;m++){
    int row = brow*BM + trow*TM + m;
    #pragma unroll
    for (int n=0;n<TN;n++){
      int col = bcol*BN + tcol*TN + n;
      P[(size_t)row*DBC_N + col] = acc[m][n];
    }
  }
}

// reduce KSPLIT partials into dbc (float4-vectorized over NTOK*DBC_N)
__global__ __launch_bounds__(256)
void reduce_pk(const float* __restrict__ part, float* __restrict__ dbc)
{
  size_t i = (size_t)blockIdx.x*256 + threadIdx.x;   // float4 index
  const size_t stride4 = (size_t)NTOK*DBC_N/4;
  float4 s = ((const float4*)part)[i];
  #pragma unroll
  for (int z=1; z<KSPLIT; ++z){
    float4 v = ((const float4*)part)[z*stride4 + i];
    s.x+=v.x; s.y+=v.y; s.z+=v.z; s.w+=v.w;
  }
  ((float4*)dbc)[i] = s;
}

// ---------------------------------------------------------------------------
// Depthwise causal conv (K=4) + bias + SiLU. xi_raw (f32, ld 2048) -> xi_post.
// ---------------------------------------------------------------------------
__global__ __launch_bounds__(256)
void conv_silu_kernel(const float* __restrict__ xi_raw,
                      const float* __restrict__ conv_w,
                      const float* __restrict__ conv_b,
                      float* __restrict__ xi_post)
{
  size_t idx = (size_t)blockIdx.x*256 + threadIdx.x;   // over NTOK*D_INNER
  int d = (int)(idx % D_INNER);
  size_t bt = idx / D_INNER;
  int t = (int)(bt % SEQ);
  size_t b = bt / SEQ;
  const float* xi = xi_raw + b*(size_t)SEQ*D_INNER;
  float accv = conv_b[d];
  #pragma unroll
  for (int k=0;k<D_CONV;k++){
    int tt = t + k - (D_CONV-1);
    if (tt >= 0) accv += xi[(size_t)tt*D_INNER + d] * conv_w[d*D_CONV + k];
  }
  xi_post[idx] = accv * sigmoidf_(accv);
}

// ---------------------------------------------------------------------------
// Chunked selective scan, pass 1: lane = channel, h[32] in registers.
// FAST PATH (runtime-verified): A_log = log(tile(arange(1..32))) is
// deterministic by problem construction -> A2[s] = A2[0]*(s+1), so
// exp(dl*A[s]) = E^(s+1) with ONE v_exp per timestep instead of 32
// (exp is quarter-rate; this was ~half the VALU issue budget).
// Falls back to general per-state exp2 if structure check fails.
// ---------------------------------------------------------------------------
__global__ __launch_bounds__(256)
void scan_part1(const float* __restrict__ dbc,     // (NTOK,128)
                const float* __restrict__ delta,   // (NTOK,D_INNER)
                const float* __restrict__ u,       // (NTOK,D_INNER)
                const float* __restrict__ A_log,   // (D_INNER,32)
                float* __restrict__ q,             // (B,NC,D_INNER,32)
                float* __restrict__ sumdl_buf)     // (B,NC,D_INNER)
{
  const int ndg  = D_INNER/256;                 // 8
  const int dgrp = blockIdx.x % ndg;
  const int c    = (blockIdx.x / ndg) % NC;
  const int b    =  blockIdx.x / (ndg*NC);
  const int d    = dgrp*256 + threadIdx.x;

  const float* Ap = A_log + (size_t)d*D_STATE;
  const float base = -__expf(Ap[0]) * LOG2E;      // log2e folded into A
  bool fastp = true;
  #pragma unroll
  for (int s=1; s<D_STATE; ++s){
    float a2 = -__expf(Ap[s]) * LOG2E;
    float ideal = base * (float)(s+1);
    fastp = fastp && (fabsf(a2 - ideal) <= 1e-4f*fabsf(ideal));
  }

  const size_t tok0 = (size_t)b*SEQ + (size_t)c*CL;
  const float* dptr = delta + tok0*D_INNER + d;
  const float* uptr = u     + tok0*D_INNER + d;
  const float* dbcp = dbc   + tok0*DBC_N;

  float h[D_STATE] = {};
  float sumdl = 0.f;

  if (fastp){
    for (int t=0; t<CL; ++t){
      float dl = dptr[(size_t)t*D_INNER];
      float uu = uptr[(size_t)t*D_INNER];
      sumdl += dl;
      float w  = dl*uu;
      float E  = exp2_fast(dl*base);
      float E2 = E*E, E3 = E2*E, E4 = E2*E2;
      float P  = 1.f;
      const float4* B4 = (const float4*)(dbcp + (size_t)t*DBC_N + DT_RANK);
      #pragma unroll
      for (int g=0; g<8; ++g){
        float4 Bv = B4[g];
        float m0 = P*E, m1 = P*E2, m2 = P*E3, m3 = P*E4;
        h[4*g+0] = m0*h[4*g+0] + w*Bv.x;
        h[4*g+1] = m1*h[4*g+1] + w*Bv.y;
        h[4*g+2] = m2*h[4*g+2] + w*Bv.z;
        h[4*g+3] = m3*h[4*g+3] + w*Bv.w;
        P = m3;
      }
    }
  } else {
    float A2[D_STATE];
    #pragma unroll
    for (int g=0; g<8; ++g){
      float4 al = *(const float4*)(Ap + 4*g);
      A2[4*g+0] = -__expf(al.x)*LOG2E; A2[4*g+1] = -__expf(al.y)*LOG2E;
      A2[4*g+2] = -__expf(al.z)*LOG2E; A2[4*g+3] = -__expf(al.w)*LOG2E;
    }
    for (int t=0; t<CL; ++t){
      float dl = dptr[(size_t)t*D_INNER];
      float uu = uptr[(size_t)t*D_INNER];
      sumdl += dl;
      float w = dl*uu;
      const float4* B4 = (const float4*)(dbcp + (size_t)t*DBC_N + DT_RANK);
      #pragma unroll
      for (int g=0; g<8; ++g){
        float4 Bv = B4[g];
        h[4*g+0] = exp2_fast(dl*A2[4*g+0])*h[4*g+0] + w*Bv.x;
        h[4*g+1] = exp2_fast(dl*A2[4*g+1])*h[4*g+1] + w*Bv.y;
        h[4*g+2] = exp2_fast(dl*A2[4*g+2])*h[4*g+2] + w*Bv.z;
        h[4*g+3] = exp2_fast(dl*A2[4*g+3])*h[4*g+3] + w*Bv.w;
      }
    }
  }

  float* qp = q + (((size_t)b*NC + c)*D_INNER + d)*D_STATE;
  #pragma unroll
  for (int g=0; g<8; ++g)
    ((float4*)qp)[g] = make_float4(h[4*g+0],h[4*g+1],h[4*g+2],h[4*g+3]);
  sumdl_buf[((size_t)b*NC + c)*D_INNER + d] = sumdl;
}

// ---------------------------------------------------------------------------
// Pass 2: sequential combine across chunks, in-place on q.
// ---------------------------------------------------------------------------
__global__ __launch_bounds__(256)
void scan_combine(float* __restrict__ q,
                  const float* __restrict__ sumdl_buf,
                  const float* __restrict__ A_log)
{
  size_t idx = (size_t)blockIdx.x*256 + threadIdx.x;   // over B*D_INNER*32
  int s = (int)(idx % D_STATE);
  size_t dd = idx / D_STATE;
  int d = (int)(dd % D_INNER);
  int b = (int)(dd / D_INNER);

  const float As2 = -__expf(A_log[(size_t)d*D_STATE + s]) * LOG2E;
  float H = 0.f;
  for (int c=0; c<NC; ++c){
    size_t off = (((size_t)b*NC + c)*D_INNER + d)*D_STATE + s;
    float tmp = q[off];          // chunk-local end state
    q[off] = H;                  // h_in for chunk c
    H = exp2_fast(As2 * sumdl_buf[((size_t)b*NC + c)*D_INNER + d]) * H + tmp;
  }
}

// ---------------------------------------------------------------------------
// Pass 3: re-run recurrence from h_in; y = sum_s h*C, fused D-skip + z-gate.
// z bf16 read, y bf16 written IN-PLACE (same slot, same thread -> race-free).
// Same fast/slow path structure as pass 1.
// ---------------------------------------------------------------------------
__global__ __launch_bounds__(256)
void scan_part2(const float* __restrict__ dbc,     // (NTOK,128)
                const float* __restrict__ delta,   // (NTOK,D_INNER)
                const float* __restrict__ u,
                u16*         __restrict__ zy,      // in: z bf16, out: y bf16
                const float* __restrict__ q,       // h_in per chunk
                const float* __restrict__ A_log,
                const float* __restrict__ Dp)
{
  const int ndg  = D_INNER/256;
  const int dgrp = blockIdx.x % ndg;
  const int c    = (blockIdx.x / ndg) % NC;
  const int b    =  blockIdx.x / (ndg*NC);
  const int d    = dgrp*256 + threadIdx.x;

  const float* Ap = A_log + (size_t)d*D_STATE;
  const float base = -__expf(Ap[0]) * LOG2E;
  bool fastp = true;
  #pragma unroll
  for (int s=1; s<D_STATE; ++s){
    float a2 = -__expf(Ap[s]) * LOG2E;
    float ideal = base * (float)(s+1);
    fastp = fastp && (fabsf(a2 - ideal) <= 1e-4f*fabsf(ideal));
  }

  float h[D_STATE];
  const float* qp = q + (((size_t)b*NC + c)*D_INNER + d)*D_STATE;
  #pragma unroll
  for (int g=0; g<8; ++g){
    float4 hv = ((const float4*)qp)[g];
    h[4*g+0]=hv.x; h[4*g+1]=hv.y; h[4*g+2]=hv.z; h[4*g+3]=hv.w;
  }
  const float Dd = Dp[d];

  const size_t tok0 = (size_t)b*SEQ + (size_t)c*CL;
  const float* dptr = delta + tok0*D_INNER + d;
  const float* uptr = u     + tok0*D_INNER + d;
  u16*         zp   = zy    + tok0*D_INNER + d;
  const float* dbcp = dbc   + tok0*DBC_N;

  if (fastp){
    for (int t=0; t<CL; ++t){
      float dl = dptr[(size_t)t*D_INNER];
      float uu = uptr[(size_t)t*D_INNER];
      float zz = bf2f(zp[(size_t)t*D_INNER]);
      float w  = dl*uu;
      float E  = exp2_fast(dl*base);
      float E2 = E*E, E3 = E2*E, E4 = E2*E2;
      float P  = 1.f;
      const float4* B4 = (const float4*)(dbcp + (size_t)t*DBC_N + DT_RANK);
      const float4* C4 = B4 + 8;
      float y = 0.f;
      #pragma unroll
      for (int g=0; g<8; ++g){
        float4 Bv = B4[g];
        float4 Cv = C4[g];
        float m0 = P*E, m1 = P*E2, m2 = P*E3, m3 = P*E4;
        h[4*g+0] = m0*h[4*g+0] + w*Bv.x;  y += h[4*g+0]*Cv.x;
        h[4*g+1] = m1*h[4*g+1] + w*Bv.y;  y += h[4*g+1]*Cv.y;
        h[4*g+2] = m2*h[4*g+2] + w*Bv.z;  y += h[4*g+2]*Cv.z;
        h[4*g+3] = m3*h[4*g+3] + w*Bv.w;  y += h[4*g+3]*Cv.w;
        P = m3;
      }
      zp[(size_t)t*D_INNER] = f2bf((y + uu*Dd) * (zz * sigmoidf_(zz)));
    }
  } else {
    float A2[D_STATE];
    #pragma unroll
    for (int g=0; g<8; ++g){
      float4 al = *(const float4*)(Ap + 4*g);
      A2[4*g+0] = -__expf(al.x)*LOG2E; A2[4*g+1] = -__expf(al.y)*LOG2E;
      A2[4*g+2] = -__expf(al.z)*LOG2E; A2[4*g+3] = -__expf(al.w)*LOG2E;
    }
    for (int t=0; t<CL; ++t){
      float dl = dptr[(size_t)t*D_INNER];
      float uu = uptr[(size_t)t*D_INNER];
      float zz = bf2f(zp[(size_t)t*D_INNER]);
      float w  = dl*uu;
      const float4* B4 = (const float4*)(dbcp + (size_t)t*DBC_N + DT_RANK);
      const float4* C4 = B4 + 8;
      float y = 0.f;
      #pragma unroll
      for (int g=0; g<8; ++g){
        float4 Bv = B4[g];
        float4 Cv = C4[g];
        h[4*g+0] = exp2_fast(dl*A2[4*g+0])*h[4*g+0] + w*Bv.x;  y += h[4*g+0]*Cv.x;
        h[4*g+1] = exp2_fast(dl*A2[4*g+1])*h[4*g+1] + w*Bv.y;  y += h[4*g+1]*Cv.y;
        h[4*g+2] = exp2_fast(dl*A2[4*g+2])*h[4*g+2] + w*Bv.z;  y += h[4*g+2]*Cv.z;
        h[4*g+3] = exp2_fast(dl*A2[4*g+3])*h[4*g+3] + w*Bv.w;  y += h[4*g+3]*Cv.w;
      }
      zp[(size_t)t*D_INNER] = f2bf((y + uu*Dd) * (zz * sigmoidf_(zz)));
    }
  }
}

// ---------------------------------------------------------------------------
// LayerNorm over last dim (1024): read f32 pre-LN, write f32 output.
// ---------------------------------------------------------------------------
__global__ __launch_bounds__(256)
void ln_kernel(const float* __restrict__ in,
               float* __restrict__ out,
               const float* __restrict__ gamma,
               const float* __restrict__ beta)
{
  const int row = blockIdx.x;
  const float* p = in + (size_t)row*D_MODEL;
  float* q = out + (size_t)row*D_MODEL;
  float v[4]; float s=0.f, ss=0.f;
  #pragma unroll
  for (int i=0;i<4;i++){
    float x = p[i*256 + threadIdx.x];
    v[i]=x; s+=x; ss+=x*x;
  }
  #pragma unroll
  for (int off=32; off; off>>=1){
    s  += __shfl_xor(s,  off, 64);
    ss += __shfl_xor(ss, off, 64);
  }
  __shared__ float sw[4], ssw[4];
  const int wid = threadIdx.x >> 6;
  if ((threadIdx.x & 63) == 0){ sw[wid]=s; ssw[wid]=ss; }
  __syncthreads();
  s  = sw[0]+sw[1]+sw[2]+sw[3];
  ss = ssw[0]+ssw[1]+ssw[2]+ssw[3];
  const float mu  = s * (1.f/D_MODEL);
  const float var = ss * (1.f/D_MODEL) - mu*mu;
  const float inv = rsqrtf(var + 1e-5f);
  #pragma unroll
  for (int i=0;i<4;i++){
    int col = i*256 + threadIdx.x;
    q[col] = (v[i]-mu)*inv*gamma[col] + beta[col];
  }
}

// ---------------------------------------------------------------------------
extern "C" void kernel_launch(void* const* d_in, const int* in_sizes, int n_in,
                              void* d_out, int out_size, void* d_ws, size_t ws_size,
                              hipStream_t stream)
{
  const float* x          = (const float*)d_in[0];   // (4,2048,1024) f32
  const float* in_proj_w  = (const float*)d_in[1];   // (1024,4096)
  const float* conv_w     = (const float*)d_in[2];   // (2048,4)
  const float* conv_b     = (const float*)d_in[3];   // (2048,)
  const float* x_proj_w   = (const float*)d_in[4];   // (2048,128)
  const float* dt_proj_w  = (const float*)d_in[5];   // (64,2048)
  const float* dt_proj_b  = (const float*)d_in[6];   // (2048,)
  const float* A_log      = (const float*)d_in[7];   // (2048,32)
  const float* Dp         = (const float*)d_in[8];   // (2048,)
  const float* out_proj_w = (const float*)d_in[9];   // (2048,1024)
  const float* ln_gamma   = (const float*)d_in[10];  // (1024,)
  const float* ln_beta    = (const float*)d_in[11];  // (1024,)
  float* out = (float*)d_out;                        // (4,2048,1024) f32 OUTPUT

  // workspace (MiB offsets), ws_size = 256 MiB:
  //   @0    xi_raw f32 64M -> pkpart f32 32M (dbc split-K) -> delta f32 -> preln
  //   @64   xi_post f32 64M
  //   @128  z bf16 32M -> y bf16 (in-place)
  //   @160  x_bf 16M (prep only) / dbc f32 4M (after x_bf dead)
  //   @164  qbuf f32 64M  [164,228)
  //   @228  sumdl f32 2M  [228,230)
  //   @230  w_inT bf16 8M [230,238)
  //   @238  w_outT bf16 4M [238,242)
  char* ws = (char*)d_ws;
  float* xi_raw  = (float*)(ws + 0);
  float* pkpart  = (float*)(ws + 0);
  float* deltab  = (float*)(ws + 0);
  float* preln   = (float*)(ws + 0);
  float* xi_post = (float*)(ws + (size_t) 67108864);
  u16*   zybuf   = (u16*)  (ws + (size_t)134217728);
  u16*   x_bf    = (u16*)  (ws + (size_t)167772160);
  float* dbc     = (float*)(ws + (size_t)167772160);
  float* qbuf    = (float*)(ws + (size_t)171966464);
  float* sumdl   = (float*)(ws + (size_t)239075328);
  u16*   w_inT   = (u16*)  (ws + (size_t)241172480);
  u16*   w_outT  = (u16*)  (ws + (size_t)249561088);

  // 0) dtype prep: x -> bf16; weights -> bf16 transposed [N][K]
  cvt_f32_bf16<<<(NTOK*(size_t)D_MODEL)/1024, 256, 0, stream>>>(x, x_bf);
  { dim3 g(4096/64, 1024/64); transpose_cvt<<<g,256,0,stream>>>(in_proj_w,  w_inT,  1024, 4096); }
  { dim3 g(1024/64, 2048/64); transpose_cvt<<<g,256,0,stream>>>(out_proj_w, w_outT, 2048, 1024); }

  // 1) merged in_proj: [xi | z] = x @ in_proj_w  (MFMA, split epilogue)
  {
    dim3 grid(2*D_INNER/128, NTOK/128);
    mfma_gemm<2><<<grid,256,0,stream>>>(D_MODEL,
        x_bf, D_MODEL, w_inT, D_MODEL, xi_raw, 0, zybuf);
  }
  // 2) xi_post = silu(conv(xi_raw) + conv_b)   (xi_raw dead after this)
  conv_silu_kernel<<<(NTOK*(size_t)D_INNER)/256,256,0,stream>>>(xi_raw, conv_w, conv_b, xi_post);

  // 3) dbc = xi_post @ x_proj_w   M=8192 N=128 K=2048, split-K over 8
  {
    dim3 grid(DBC_N/64, NTOK/64, KSPLIT);       // 2048 blocks
    sgemm_pk<<<grid,256,0,stream>>>(D_INNER,
        xi_post,D_INNER, x_proj_w,DBC_N, pkpart);
    reduce_pk<<<(NTOK*(size_t)DBC_N)/1024,256,0,stream>>>(pkpart, dbc);
  }
  // 4) delta = softplus(dbc[:, :64] @ dt_proj_w + b)  M=8192 N=2048 K=64 -> @0
  {
    dim3 grid(D_INNER/64, NTOK/64);
    sgemm<64,64,16,4,4,1><<<grid,256,0,stream>>>(DT_RANK,
        dbc,DBC_N, dt_proj_w,D_INNER, deltab,D_INNER, dt_proj_b);
  }
  // 5) chunked scan (NC=64); part2 writes y bf16 in-place over z
  {
    dim3 grid1((D_INNER/256)*NC*BATCH);           // 2048 blocks
    scan_part1<<<grid1,256,0,stream>>>(dbc, deltab, xi_post, A_log, qbuf, sumdl);
    scan_combine<<<(BATCH*(size_t)D_INNER*D_STATE)/256,256,0,stream>>>(qbuf, sumdl, A_log);
    scan_part2<<<grid1,256,0,stream>>>(dbc, deltab, xi_post, zybuf, qbuf, A_log, Dp);
  }
  // 6) preln = y @ out_proj_w              (MFMA, f32 out) -> @0
  {
    dim3 grid(D_MODEL/128, NTOK/128);
    mfma_gemm<0><<<grid,256,0,stream>>>(D_INNER,
        zybuf, D_INNER, w_outT, D_INNER, preln, D_MODEL, nullptr);
  }
  // 7) LayerNorm: preln f32 -> out f32
  ln_kernel<<<NTOK,256,0,stream>>>(preln, out, ln_gamma, ln_beta);
}

// Round 2
// 664.711 us; speedup vs baseline: 1.1315x; 1.0212x over previous
//
#include <hip/hip_runtime.h>
#include <math.h>

#define D_MODEL 1024
#define D_STATE 32
#define D_CONV  4
#define D_INNER 2048
#define DT_RANK 64
#define BATCH   4
#define SEQ     2048
#define NTOK    (BATCH*SEQ)            // 8192 rows
#define DBC_N   (DT_RANK + 2*D_STATE)  // 128
#define NC      64                     // scan chunks
#define CL      (SEQ/NC)               // 32 steps per chunk
#define KSPLIT  8                      // split-K factor for dbc GEMM
#define LOG2E   1.4426950408889634f

typedef unsigned short u16;
typedef short bf16x8 __attribute__((ext_vector_type(8)));
typedef float f32x4  __attribute__((ext_vector_type(4)));

__device__ __forceinline__ float bf2f(u16 u){
  return __uint_as_float(((unsigned)u) << 16);
}
__device__ __forceinline__ u16 f2bf(float f){   // round-to-nearest-even
  unsigned u = __float_as_uint(f);
  return (u16)((u + 0x7fffu + ((u >> 16) & 1u)) >> 16);
}
__device__ __forceinline__ float sigmoidf_(float x){ return 1.f/(1.f+__expf(-x)); }
// raw v_exp_f32: r = 2^x (1 instruction; __expf = mul + this)
__device__ __forceinline__ float exp2_fast(float x){
  float r;
  asm("v_exp_f32 %0, %1" : "=v"(r) : "v"(x));
  return r;
}

typedef __attribute__((address_space(3))) void       lds_v;
typedef const __attribute__((address_space(1))) void gl_v;
#define GLOAD_LDS16(g, l) \
  __builtin_amdgcn_global_load_lds((gl_v*)(g), (lds_v*)(l), 16, 0, 0)

// ---------------------------------------------------------------------------
// bf16 MFMA GEMM: C = A[M,K] @ W[K,N], A bf16 row-major [M][K], B = weight
// PRE-TRANSPOSED bf16 [N][K]. 128x128 tile, BK=32, 4 waves of 64x64.
// Staging via global_load_lds width=16 into LINEAR [128][32] LDS.
// BANK-CONFLICT SWIZZLE (rule #21: both-sides-or-neither): DMA dest must be
// linear, so the 16B chunk-within-row is permuted on the GLOBAL SOURCE side
// (c_src = c_dest ^ ((row>>1)&3)) and the same XOR is applied on ds_read.
// Read bank-quad = 4*(fr&1) | (fq ^ ((fr>>1)&3)) -> all 8 quads hit exactly
// twice per 16-lane group (was 2 quads x 8 lanes = 8.4M conflicts/dispatch).
// MODE 0: f32 store. MODE 2 (split in_proj): col<D_INNER -> f32 C1;
// col>=D_INNER -> bf16 C2@col-2048.
// ---------------------------------------------------------------------------
template<int MODE>
__global__ __launch_bounds__(256)
void mfma_gemm(int K,
               const u16* __restrict__ A, int lda,
               const u16* __restrict__ B, int ldb,   // [N][K]
               void* __restrict__ C1, int ldc,
               u16*  __restrict__ C2)
{
  __shared__ u16 As[128*32];
  __shared__ u16 Bs[128*32];
  const int tid  = threadIdx.x;
  const int lane = tid & 63;
  const int wave = tid >> 6;
  const int wm = (wave>>1)*64, wn = (wave&1)*64;
  const int m0 = blockIdx.y*128, n0 = blockIdx.x*128;

  const int srow = tid >> 2;        // 0..63 (row within 64-row half-tile)
  // swizzled source chunk: logical chunk stored at dest chunk (tid&3)
  const int scs  = (((tid & 3) ^ ((srow >> 1) & 3)) * 8);

  const u16* Ag = A + (size_t)(m0 + srow)*lda + scs;
  const u16* Bg = B + (size_t)(n0 + srow)*ldb + scs;

  const int fr = lane & 15;         // fragment row within 16
  const int fq = lane >> 4;         // quad: k-chunk of 8
  const int sx = (fr >> 1) & 3;     // read-side XOR (loop-invariant)
  const int rdoff = ((fq ^ sx) * 8);
  f32x4 acc[4][4] = {};

  u16* as0 = &As[tid*8];
  u16* as1 = &As[2048 + tid*8];
  u16* bs0 = &Bs[tid*8];
  u16* bs1 = &Bs[2048 + tid*8];

  for (int k0=0; k0<K; k0+=32){
    GLOAD_LDS16(Ag + k0,                    as0);
    GLOAD_LDS16(Ag + (size_t)64*lda + k0,   as1);
    GLOAD_LDS16(Bg + k0,                    bs0);
    GLOAD_LDS16(Bg + (size_t)64*ldb + k0,   bs1);
    __syncthreads();                 // drains vmcnt -> LDS tile ready

    bf16x8 af[4], bfr[4];
    #pragma unroll
    for (int i=0;i<4;i++){
      af[i]  = *(const bf16x8*)&As[(wm + i*16 + fr)*32 + rdoff];
      bfr[i] = *(const bf16x8*)&Bs[(wn + i*16 + fr)*32 + rdoff];
    }
    #pragma unroll
    for (int mi=0;mi<4;mi++)
      #pragma unroll
      for (int ni=0;ni<4;ni++)
        acc[mi][ni] = __builtin_amdgcn_mfma_f32_16x16x32_bf16(
            af[mi], bfr[ni], acc[mi][ni], 0, 0, 0);
    __syncthreads();                 // all reads done before next overwrite
  }

  // C/D layout: row = fq*4 + r, col = fr  (m89-verified)
  const bool second = (MODE==2) && (n0 >= D_INNER);   // block-uniform
  #pragma unroll
  for (int mi=0;mi<4;mi++){
    #pragma unroll
    for (int ni=0;ni<4;ni++){
      int col = n0 + wn + ni*16 + fr;
      #pragma unroll
      for (int r=0;r<4;r++){
        int row = m0 + wm + mi*16 + fq*4 + r;
        float v = acc[mi][ni][r];
        if (MODE==0)      ((float*)C1)[(size_t)row*ldc + col] = v;
        else {
          if (second) C2[(size_t)row*D_INNER + (col - D_INNER)] = f2bf(v);
          else        ((float*)C1)[(size_t)row*D_INNER + col] = v;
        }
      }
    }
  }
}

// ---------------------------------------------------------------------------
// f32 -> bf16 elementwise (n multiple of 1024)
// ---------------------------------------------------------------------------
__global__ __launch_bounds__(256)
void cvt_f32_bf16(const float* __restrict__ in, u16* __restrict__ out)
{
  size_t i = (size_t)blockIdx.x*256 + threadIdx.x;
  float4 v = ((const float4*)in)[i];
  ushort4 o;
  o.x=f2bf(v.x); o.y=f2bf(v.y); o.z=f2bf(v.z); o.w=f2bf(v.w);
  ((ushort4*)out)[i] = o;
}

// ---------------------------------------------------------------------------
// f32 [R][C] -> bf16 [C][R] transpose+convert, 64x64 tiles, 256 threads.
// ---------------------------------------------------------------------------
__global__ __launch_bounds__(256)
void transpose_cvt(const float* __restrict__ in, u16* __restrict__ out,
                   int R, int C)
{
  __shared__ float tile[64][65];
  const int bc = blockIdx.x*64, br = blockIdx.y*64;
  const int tx = threadIdx.x & 63, ty = threadIdx.x >> 6;
  #pragma unroll
  for (int i=0;i<16;i++){
    int r = ty + i*4;
    tile[r][tx] = in[(size_t)(br+r)*C + bc+tx];
  }
  __syncthreads();
  #pragma unroll
  for (int i=0;i<16;i++){
    int r = ty + i*4;
    out[(size_t)(bc+r)*R + br+tx] = f2bf(tile[tx][r]);
  }
}

// ---------------------------------------------------------------------------
// f32 tiled GEMM: C[M,N] = A[M,K] @ B[K,N]
// EPI: 0 plain, 1 softplus(acc + bias[col]).
// ---------------------------------------------------------------------------
template<int BM,int BN,int BK,int TM,int TN,int EPI>
__global__ __launch_bounds__((BM/TM)*(BN/TN))
void sgemm(int K,
           const float* __restrict__ A,int lda,
           const float* __restrict__ B,int ldb,
           float* __restrict__ C,int ldc,
           const float* __restrict__ bias)
{
  __shared__ float As[BK][BM];
  __shared__ float Bs[BK][BN];
  const int tid  = threadIdx.x;
  const int brow = blockIdx.y, bcol = blockIdx.x;
  const int tcol = tid % (BN/TN);
  const int trow = tid / (BN/TN);

  const float* Ag = A + (size_t)brow*BM*lda;
  const float* Bg = B + (size_t)bcol*BN;

  const int arow = tid / (BK/4);
  const int acol = (tid % (BK/4))*4;
  const int brw  = tid / (BN/4);
  const int bcv  = (tid % (BN/4))*4;

  float acc[TM][TN] = {};

  for (int k0=0; k0<K; k0+=BK){
    float4 av = *(const float4*)(Ag + (size_t)arow*lda + k0 + acol);
    float4 bv = *(const float4*)(Bg + (size_t)(k0+brw)*ldb + bcv);
    __syncthreads();
    As[acol+0][arow]=av.x; As[acol+1][arow]=av.y;
    As[acol+2][arow]=av.z; As[acol+3][arow]=av.w;
    *(float4*)&Bs[brw][bcv] = bv;
    __syncthreads();
    #pragma unroll
    for (int kk=0;kk<BK;kk++){
      float ra[TM], rb[TN];
      #pragma unroll
      for (int m=0;m<TM;m++) ra[m]=As[kk][trow*TM+m];
      #pragma unroll
      for (int n=0;n<TN;n++) rb[n]=Bs[kk][tcol*TN+n];
      #pragma unroll
      for (int m=0;m<TM;m++)
        #pragma unroll
        for (int n=0;n<TN;n++)
          acc[m][n] += ra[m]*rb[n];
    }
  }

  #pragma unroll
  for (int m=0;m<TM;m++){
    int row = brow*BM + trow*TM + m;
    #pragma unroll
    for (int n=0;n<TN;n++){
      int col = bcol*BN + tcol*TN + n;
      float v = acc[m][n];
      if (EPI==1){
        v += bias[col];
        v = (v > 20.f) ? v : log1pf(__expf(v));
      }
      C[(size_t)row*ldc + col] = v;
    }
  }
}

// ---------------------------------------------------------------------------
// Split-K f32 GEMM (dbc): partial[z] = A[:, zKc:(z+1)Kc] @ B[zKc:, :]
// 64x64 tile, BK=16. grid = (N/64, M/64, KSPLIT). Kc = K/KSPLIT.
// ---------------------------------------------------------------------------
__global__ __launch_bounds__(256)
void sgemm_pk(int K,
              const float* __restrict__ A,int lda,
              const float* __restrict__ B,int ldb,
              float* __restrict__ part)          // (KSPLIT, NTOK, DBC_N)
{
  const int BM=64, BN=64, BK=16, TM=4, TN=4;
  __shared__ float As[BK][BM];
  __shared__ float Bs[BK][BN];
  const int tid  = threadIdx.x;
  const int brow = blockIdx.y, bcol = blockIdx.x, kz = blockIdx.z;
  const int Kc   = K / KSPLIT;
  const int tcol = tid % (BN/TN);
  const int trow = tid / (BN/TN);

  const float* Ag = A + (size_t)brow*BM*lda + (size_t)kz*Kc;
  const float* Bg = B + (size_t)kz*Kc*ldb + (size_t)bcol*BN;

  const int arow = tid / (BK/4);
  const int acol = (tid % (BK/4))*4;
  const int brw  = tid / (BN/4);
  const int bcv  = (tid % (BN/4))*4;

  float acc[TM][TN] = {};

  for (int k0=0; k0<Kc; k0+=BK){
    float4 av = *(const float4*)(Ag + (size_t)arow*lda + k0 + acol);
    float4 bv = *(const float4*)(Bg + (size_t)(k0+brw)*ldb + bcv);
    __syncthreads();
    As[acol+0][arow]=av.x; As[acol+1][arow]=av.y;
    As[acol+2][arow]=av.z; As[acol+3][arow]=av.w;
    *(float4*)&Bs[brw][bcv] = bv;
    __syncthreads();
    #pragma unroll
    for (int kk=0;kk<BK;kk++){
      float ra[TM], rb[TN];
      #pragma unroll
      for (int m=0;m<TM;m++) ra[m]=As[kk][trow*TM+m];
      #pragma unroll
      for (int n=0;n<TN;n++) rb[n]=Bs[kk][tcol*TN+n];
      #pragma unroll
      for (int m=0;m<TM;m++)
        #pragma unroll
        for (int n=0;n<TN;n++)
          acc[m][n] += ra[m]*rb[n];
    }
  }

  float* P = part + (size_t)kz*NTOK*DBC_N;
  #pragma unroll
  for (int m=0;m<TM;m++){
    int row = brow*BM + trow*TM + m;
    #pragma unroll
    for (int n=0;n<TN;n++){
      int col = bcol*BN + tcol*TN + n;
      P[(size_t)row*DBC_N + col] = acc[m][n];
    }
  }
}

// reduce KSPLIT partials into dbc (float4-vectorized over NTOK*DBC_N)
__global__ __launch_bounds__(256)
void reduce_pk(const float* __restrict__ part, float* __restrict__ dbc)
{
  size_t i = (size_t)blockIdx.x*256 + threadIdx.x;   // float4 index
  const size_t stride4 = (size_t)NTOK*DBC_N/4;
  float4 s = ((const float4*)part)[i];
  #pragma unroll
  for (int z=1; z<KSPLIT; ++z){
    float4 v = ((const float4*)part)[z*stride4 + i];
    s.x+=v.x; s.y+=v.y; s.z+=v.z; s.w+=v.w;
  }
  ((float4*)dbc)[i] = s;
}

// ---------------------------------------------------------------------------
// Depthwise causal conv (K=4) + bias + SiLU. xi_raw (f32, ld 2048) -> xi_post.
// ---------------------------------------------------------------------------
__global__ __launch_bounds__(256)
void conv_silu_kernel(const float* __restrict__ xi_raw,
                      const float* __restrict__ conv_w,
                      const float* __restrict__ conv_b,
                      float* __restrict__ xi_post)
{
  size_t idx = (size_t)blockIdx.x*256 + threadIdx.x;   // over NTOK*D_INNER
  int d = (int)(idx % D_INNER);
  size_t bt = idx / D_INNER;
  int t = (int)(bt % SEQ);
  size_t b = bt / SEQ;
  const float* xi = xi_raw + b*(size_t)SEQ*D_INNER;
  float accv = conv_b[d];
  #pragma unroll
  for (int k=0;k<D_CONV;k++){
    int tt = t + k - (D_CONV-1);
    if (tt >= 0) accv += xi[(size_t)tt*D_INNER + d] * conv_w[d*D_CONV + k];
  }
  xi_post[idx] = accv * sigmoidf_(accv);
}

// ---------------------------------------------------------------------------
// Chunked selective scan, pass 1: lane = channel, h[32] in registers.
// FAST PATH (runtime-verified): A_log = log(tile(arange(1..32))) is
// deterministic by problem construction -> A2[s] = A2[0]*(s+1), so
// exp(dl*A[s]) = E^(s+1) with ONE v_exp per timestep instead of 32.
// Falls back to general per-state exp2 if structure check fails.
// ---------------------------------------------------------------------------
__global__ __launch_bounds__(256)
void scan_part1(const float* __restrict__ dbc,     // (NTOK,128)
                const float* __restrict__ delta,   // (NTOK,D_INNER)
                const float* __restrict__ u,       // (NTOK,D_INNER)
                const float* __restrict__ A_log,   // (D_INNER,32)
                float* __restrict__ q,             // (B,NC,D_INNER,32)
                float* __restrict__ sumdl_buf)     // (B,NC,D_INNER)
{
  const int ndg  = D_INNER/256;                 // 8
  const int dgrp = blockIdx.x % ndg;
  const int c    = (blockIdx.x / ndg) % NC;
  const int b    =  blockIdx.x / (ndg*NC);
  const int d    = dgrp*256 + threadIdx.x;

  const float* Ap = A_log + (size_t)d*D_STATE;
  const float base = -__expf(Ap[0]) * LOG2E;      // log2e folded into A
  bool fastp = true;
  #pragma unroll
  for (int s=1; s<D_STATE; ++s){
    float a2 = -__expf(Ap[s]) * LOG2E;
    float ideal = base * (float)(s+1);
    fastp = fastp && (fabsf(a2 - ideal) <= 1e-4f*fabsf(ideal));
  }

  const size_t tok0 = (size_t)b*SEQ + (size_t)c*CL;
  const float* dptr = delta + tok0*D_INNER + d;
  const float* uptr = u     + tok0*D_INNER + d;
  const float* dbcp = dbc   + tok0*DBC_N;

  float h[D_STATE] = {};
  float sumdl = 0.f;

  if (fastp){
    for (int t=0; t<CL; ++t){
      float dl = dptr[(size_t)t*D_INNER];
      float uu = uptr[(size_t)t*D_INNER];
      sumdl += dl;
      float w  = dl*uu;
      float E  = exp2_fast(dl*base);
      float E2 = E*E, E3 = E2*E, E4 = E2*E2;
      float P  = 1.f;
      const float4* B4 = (const float4*)(dbcp + (size_t)t*DBC_N + DT_RANK);
      #pragma unroll
      for (int g=0; g<8; ++g){
        float4 Bv = B4[g];
        float m0 = P*E, m1 = P*E2, m2 = P*E3, m3 = P*E4;
        h[4*g+0] = m0*h[4*g+0] + w*Bv.x;
        h[4*g+1] = m1*h[4*g+1] + w*Bv.y;
        h[4*g+2] = m2*h[4*g+2] + w*Bv.z;
        h[4*g+3] = m3*h[4*g+3] + w*Bv.w;
        P = m3;
      }
    }
  } else {
    float A2[D_STATE];
    #pragma unroll
    for (int g=0; g<8; ++g){
      float4 al = *(const float4*)(Ap + 4*g);
      A2[4*g+0] = -__expf(al.x)*LOG2E; A2[4*g+1] = -__expf(al.y)*LOG2E;
      A2[4*g+2] = -__expf(al.z)*LOG2E; A2[4*g+3] = -__expf(al.w)*LOG2E;
    }
    for (int t=0; t<CL; ++t){
      float dl = dptr[(size_t)t*D_INNER];
      float uu = uptr[(size_t)t*D_INNER];
      sumdl += dl;
      float w = dl*uu;
      const float4* B4 = (const float4*)(dbcp + (size_t)t*DBC_N + DT_RANK);
      #pragma unroll
      for (int g=0; g<8; ++g){
        float4 Bv = B4[g];
        h[4*g+0] = exp2_fast(dl*A2[4*g+0])*h[4*g+0] + w*Bv.x;
        h[4*g+1] = exp2_fast(dl*A2[4*g+1])*h[4*g+1] + w*Bv.y;
        h[4*g+2] = exp2_fast(dl*A2[4*g+2])*h[4*g+2] + w*Bv.z;
        h[4*g+3] = exp2_fast(dl*A2[4*g+3])*h[4*g+3] + w*Bv.w;
      }
    }
  }

  float* qp = q + (((size_t)b*NC + c)*D_INNER + d)*D_STATE;
  #pragma unroll
  for (int g=0; g<8; ++g)
    ((float4*)qp)[g] = make_float4(h[4*g+0],h[4*g+1],h[4*g+2],h[4*g+3]);
  sumdl_buf[((size_t)b*NC + c)*D_INNER + d] = sumdl;
}

// ---------------------------------------------------------------------------
// Pass 2: sequential combine across chunks, in-place on q.
// ---------------------------------------------------------------------------
__global__ __launch_bounds__(256)
void scan_combine(float* __restrict__ q,
                  const float* __restrict__ sumdl_buf,
                  const float* __restrict__ A_log)
{
  size_t idx = (size_t)blockIdx.x*256 + threadIdx.x;   // over B*D_INNER*32
  int s = (int)(idx % D_STATE);
  size_t dd = idx / D_STATE;
  int d = (int)(dd % D_INNER);
  int b = (int)(dd / D_INNER);

  const float As2 = -__expf(A_log[(size_t)d*D_STATE + s]) * LOG2E;
  float H = 0.f;
  for (int c=0; c<NC; ++c){
    size_t off = (((size_t)b*NC + c)*D_INNER + d)*D_STATE + s;
    float tmp = q[off];          // chunk-local end state
    q[off] = H;                  // h_in for chunk c
    H = exp2_fast(As2 * sumdl_buf[((size_t)b*NC + c)*D_INNER + d]) * H + tmp;
  }
}

// ---------------------------------------------------------------------------
// Pass 3: re-run recurrence from h_in; y = sum_s h*C, fused D-skip + z-gate.
// z bf16 read, y bf16 written IN-PLACE (same slot, same thread -> race-free).
// Same fast/slow path structure as pass 1.
// ---------------------------------------------------------------------------
__global__ __launch_bounds__(256)
void scan_part2(const float* __restrict__ dbc,     // (NTOK,128)
                const float* __restrict__ delta,   // (NTOK,D_INNER)
                const float* __restrict__ u,
                u16*         __restrict__ zy,      // in: z bf16, out: y bf16
                const float* __restrict__ q,       // h_in per chunk
                const float* __restrict__ A_log,
                const float* __restrict__ Dp)
{
  const int ndg  = D_INNER/256;
  const int dgrp = blockIdx.x % ndg;
  const int c    = (blockIdx.x / ndg) % NC;
  const int b    =  blockIdx.x / (ndg*NC);
  const int d    = dgrp*256 + threadIdx.x;

  const float* Ap = A_log + (size_t)d*D_STATE;
  const float base = -__expf(Ap[0]) * LOG2E;
  bool fastp = true;
  #pragma unroll
  for (int s=1; s<D_STATE; ++s){
    float a2 = -__expf(Ap[s]) * LOG2E;
    float ideal = base * (float)(s+1);
    fastp = fastp && (fabsf(a2 - ideal) <= 1e-4f*fabsf(ideal));
  }

  float h[D_STATE];
  const float* qp = q + (((size_t)b*NC + c)*D_INNER + d)*D_STATE;
  #pragma unroll
  for (int g=0; g<8; ++g){
    float4 hv = ((const float4*)qp)[g];
    h[4*g+0]=hv.x; h[4*g+1]=hv.y; h[4*g+2]=hv.z; h[4*g+3]=hv.w;
  }
  const float Dd = Dp[d];

  const size_t tok0 = (size_t)b*SEQ + (size_t)c*CL;
  const float* dptr = delta + tok0*D_INNER + d;
  const float* uptr = u     + tok0*D_INNER + d;
  u16*         zp   = zy    + tok0*D_INNER + d;
  const float* dbcp = dbc   + tok0*DBC_N;

  if (fastp){
    for (int t=0; t<CL; ++t){
      float dl = dptr[(size_t)t*D_INNER];
      float uu = uptr[(size_t)t*D_INNER];
      float zz = bf2f(zp[(size_t)t*D_INNER]);
      float w  = dl*uu;
      float E  = exp2_fast(dl*base);
      float E2 = E*E, E3 = E2*E, E4 = E2*E2;
      float P  = 1.f;
      const float4* B4 = (const float4*)(dbcp + (size_t)t*DBC_N + DT_RANK);
      const float4* C4 = B4 + 8;
      float y = 0.f;
      #pragma unroll
      for (int g=0; g<8; ++g){
        float4 Bv = B4[g];
        float4 Cv = C4[g];
        float m0 = P*E, m1 = P*E2, m2 = P*E3, m3 = P*E4;
        h[4*g+0] = m0*h[4*g+0] + w*Bv.x;  y += h[4*g+0]*Cv.x;
        h[4*g+1] = m1*h[4*g+1] + w*Bv.y;  y += h[4*g+1]*Cv.y;
        h[4*g+2] = m2*h[4*g+2] + w*Bv.z;  y += h[4*g+2]*Cv.z;
        h[4*g+3] = m3*h[4*g+3] + w*Bv.w;  y += h[4*g+3]*Cv.w;
        P = m3;
      }
      zp[(size_t)t*D_INNER] = f2bf((y + uu*Dd) * (zz * sigmoidf_(zz)));
    }
  } else {
    float A2[D_STATE];
    #pragma unroll
    for (int g=0; g<8; ++g){
      float4 al = *(const float4*)(Ap + 4*g);
      A2[4*g+0] = -__expf(al.x)*LOG2E; A2[4*g+1] = -__expf(al.y)*LOG2E;
      A2[4*g+2] = -__expf(al.z)*LOG2E; A2[4*g+3] = -__expf(al.w)*LOG2E;
    }
    for (int t=0; t<CL; ++t){
      float dl = dptr[(size_t)t*D_INNER];
      float uu = uptr[(size_t)t*D_INNER];
      float zz = bf2f(zp[(size_t)t*D_INNER]);
      float w  = dl*uu;
      const float4* B4 = (const float4*)(dbcp + (size_t)t*DBC_N + DT_RANK);
      const float4* C4 = B4 + 8;
      float y = 0.f;
      #pragma unroll
      for (int g=0; g<8; ++g){
        float4 Bv = B4[g];
        float4 Cv = C4[g];
        h[4*g+0] = exp2_fast(dl*A2[4*g+0])*h[4*g+0] + w*Bv.x;  y += h[4*g+0]*Cv.x;
        h[4*g+1] = exp2_fast(dl*A2[4*g+1])*h[4*g+1] + w*Bv.y;  y += h[4*g+1]*Cv.y;
        h[4*g+2] = exp2_fast(dl*A2[4*g+2])*h[4*g+2] + w*Bv.z;  y += h[4*g+2]*Cv.z;
        h[4*g+3] = exp2_fast(dl*A2[4*g+3])*h[4*g+3] + w*Bv.w;  y += h[4*g+3]*Cv.w;
      }
      zp[(size_t)t*D_INNER] = f2bf((y + uu*Dd) * (zz * sigmoidf_(zz)));
    }
  }
}

// ---------------------------------------------------------------------------
// LayerNorm over last dim (1024): read f32 pre-LN, write f32 output.
// ---------------------------------------------------------------------------
__global__ __launch_bounds__(256)
void ln_kernel(const float* __restrict__ in,
               float* __restrict__ out,
               const float* __restrict__ gamma,
               const float* __restrict__ beta)
{
  const int row = blockIdx.x;
  const float* p = in + (size_t)row*D_MODEL;
  float* q = out + (size_t)row*D_MODEL;
  float v[4]; float s=0.f, ss=0.f;
  #pragma unroll
  for (int i=0;i<4;i++){
    float x = p[i*256 + threadIdx.x];
    v[i]=x; s+=x; ss+=x*x;
  }
  #pragma unroll
  for (int off=32; off; off>>=1){
    s  += __shfl_xor(s,  off, 64);
    ss += __shfl_xor(ss, off, 64);
  }
  __shared__ float sw[4], ssw[4];
  const int wid = threadIdx.x >> 6;
  if ((threadIdx.x & 63) == 0){ sw[wid]=s; ssw[wid]=ss; }
  __syncthreads();
  s  = sw[0]+sw[1]+sw[2]+sw[3];
  ss = ssw[0]+ssw[1]+ssw[2]+ssw[3];
  const float mu  = s * (1.f/D_MODEL);
  const float var = ss * (1.f/D_MODEL) - mu*mu;
  const float inv = rsqrtf(var + 1e-5f);
  #pragma unroll
  for (int i=0;i<4;i++){
    int col = i*256 + threadIdx.x;
    q[col] = (v[i]-mu)*inv*gamma[col] + beta[col];
  }
}

// ---------------------------------------------------------------------------
extern "C" void kernel_launch(void* const* d_in, const int* in_sizes, int n_in,
                              void* d_out, int out_size, void* d_ws, size_t ws_size,
                              hipStream_t stream)
{
  const float* x          = (const float*)d_in[0];   // (4,2048,1024) f32
  const float* in_proj_w  = (const float*)d_in[1];   // (1024,4096)
  const float* conv_w     = (const float*)d_in[2];   // (2048,4)
  const float* conv_b     = (const float*)d_in[3];   // (2048,)
  const float* x_proj_w   = (const float*)d_in[4];   // (2048,128)
  const float* dt_proj_w  = (const float*)d_in[5];   // (64,2048)
  const float* dt_proj_b  = (const float*)d_in[6];   // (2048,)
  const float* A_log      = (const float*)d_in[7];   // (2048,32)
  const float* Dp         = (const float*)d_in[8];   // (2048,)
  const float* out_proj_w = (const float*)d_in[9];   // (2048,1024)
  const float* ln_gamma   = (const float*)d_in[10];  // (1024,)
  const float* ln_beta    = (const float*)d_in[11];  // (1024,)
  float* out = (float*)d_out;                        // (4,2048,1024) f32 OUTPUT

  // workspace (MiB offsets), ws_size = 256 MiB:
  //   @0    xi_raw f32 64M -> pkpart f32 32M (dbc split-K) -> delta f32 -> preln
  //   @64   xi_post f32 64M
  //   @128  z bf16 32M -> y bf16 (in-place)
  //   @160  x_bf 16M (prep only) / dbc f32 4M (after x_bf dead)
  //   @164  qbuf f32 64M  [164,228)
  //   @228  sumdl f32 2M  [228,230)
  //   @230  w_inT bf16 8M [230,238)
  //   @238  w_outT bf16 4M [238,242)
  char* ws = (char*)d_ws;
  float* xi_raw  = (float*)(ws + 0);
  float* pkpart  = (float*)(ws + 0);
  float* deltab  = (float*)(ws + 0);
  float* preln   = (float*)(ws + 0);
  float* xi_post = (float*)(ws + (size_t) 67108864);
  u16*   zybuf   = (u16*)  (ws + (size_t)134217728);
  u16*   x_bf    = (u16*)  (ws + (size_t)167772160);
  float* dbc     = (float*)(ws + (size_t)167772160);
  float* qbuf    = (float*)(ws + (size_t)171966464);
  float* sumdl   = (float*)(ws + (size_t)239075328);
  u16*   w_inT   = (u16*)  (ws + (size_t)241172480);
  u16*   w_outT  = (u16*)  (ws + (size_t)249561088);

  // 0) dtype prep: x -> bf16; weights -> bf16 transposed [N][K]
  cvt_f32_bf16<<<(NTOK*(size_t)D_MODEL)/1024, 256, 0, stream>>>(x, x_bf);
  { dim3 g(4096/64, 1024/64); transpose_cvt<<<g,256,0,stream>>>(in_proj_w,  w_inT,  1024, 4096); }
  { dim3 g(1024/64, 2048/64); transpose_cvt<<<g,256,0,stream>>>(out_proj_w, w_outT, 2048, 1024); }

  // 1) merged in_proj: [xi | z] = x @ in_proj_w  (MFMA, split epilogue)
  {
    dim3 grid(2*D_INNER/128, NTOK/128);
    mfma_gemm<2><<<grid,256,0,stream>>>(D_MODEL,
        x_bf, D_MODEL, w_inT, D_MODEL, xi_raw, 0, zybuf);
  }
  // 2) xi_post = silu(conv(xi_raw) + conv_b)   (xi_raw dead after this)
  conv_silu_kernel<<<(NTOK*(size_t)D_INNER)/256,256,0,stream>>>(xi_raw, conv_w, conv_b, xi_post);

  // 3) dbc = xi_post @ x_proj_w   M=8192 N=128 K=2048, split-K over 8
  {
    dim3 grid(DBC_N/64, NTOK/64, KSPLIT);       // 2048 blocks
    sgemm_pk<<<grid,256,0,stream>>>(D_INNER,
        xi_post,D_INNER, x_proj_w,DBC_N, pkpart);
    reduce_pk<<<(NTOK*(size_t)DBC_N)/1024,256,0,stream>>>(pkpart, dbc);
  }
  // 4) delta = softplus(dbc[:, :64] @ dt_proj_w + b)  M=8192 N=2048 K=64 -> @0
  {
    dim3 grid(D_INNER/64, NTOK/64);
    sgemm<64,64,16,4,4,1><<<grid,256,0,stream>>>(DT_RANK,
        dbc,DBC_N, dt_proj_w,D_INNER, deltab,D_INNER, dt_proj_b);
  }
  // 5) chunked scan (NC=64); part2 writes y bf16 in-place over z
  {
    dim3 grid1((D_INNER/256)*NC*BATCH);           // 2048 blocks
    scan_part1<<<grid1,256,0,stream>>>(dbc, deltab, xi_post, A_log, qbuf, sumdl);
    scan_combine<<<(BATCH*(size_t)D_INNER*D_STATE)/256,256,0,stream>>>(qbuf, sumdl, A_log);
    scan_part2<<<grid1,256,0,stream>>>(dbc, deltab, xi_post, zybuf, qbuf, A_log, Dp);
  }
  // 6) preln = y @ out_proj_w              (MFMA, f32 out) -> @0
  {
    dim3 grid(D_MODEL/128, NTOK/128);
    mfma_gemm<0><<<grid,256,0,stream>>>(D_INNER,
        zybuf, D_INNER, w_outT, D_INNER, preln, D_MODEL, nullptr);
  }
  // 7) LayerNorm: preln f32 -> out f32
  ln_kernel<<<NTOK,256,0,stream>>>(preln, out, ln_gamma, ln_beta);
}

// Round 3
// 623.042 us; speedup vs baseline: 1.2071x; 1.0669x over previous
//
#include <hip/hip_runtime.h>
#include <math.h>

#define D_MODEL 1024
#define D_STATE 32
#define D_CONV  4
#define D_INNER 2048
#define DT_RANK 64
#define BATCH   4
#define SEQ     2048
#define NTOK    (BATCH*SEQ)            // 8192 rows
#define DBC_N   (DT_RANK + 2*D_STATE)  // 128
#define NC      64                     // scan chunks
#define CL      (SEQ/NC)               // 32 steps per chunk
#define KSPLIT  8                      // split-K factor for dbc GEMM
#define LOG2E   1.4426950408889634f

typedef unsigned short u16;
typedef short bf16x8 __attribute__((ext_vector_type(8)));
typedef float f32x4  __attribute__((ext_vector_type(4)));

__device__ __forceinline__ float bf2f(u16 u){
  return __uint_as_float(((unsigned)u) << 16);
}
__device__ __forceinline__ u16 f2bf(float f){   // round-to-nearest-even
  unsigned u = __float_as_uint(f);
  return (u16)((u + 0x7fffu + ((u >> 16) & 1u)) >> 16);
}
__device__ __forceinline__ float sigmoidf_(float x){ return 1.f/(1.f+__expf(-x)); }
// raw v_exp_f32: r = 2^x (1 instruction; __expf = mul + this)
__device__ __forceinline__ float exp2_fast(float x){
  float r;
  asm("v_exp_f32 %0, %1" : "=v"(r) : "v"(x));
  return r;
}

typedef __attribute__((address_space(3))) void       lds_v;
typedef const __attribute__((address_space(1))) void gl_v;
#define GLOAD_LDS16(g, l) \
  __builtin_amdgcn_global_load_lds((gl_v*)(g), (lds_v*)(l), 16, 0, 0)

// ---------------------------------------------------------------------------
// bf16 MFMA GEMM: C = A[M,K] @ W[K,N], A bf16 row-major [M][K], B = weight
// PRE-TRANSPOSED bf16 [N][K]. 128x128 tile, BK=32, 4 waves of 64x64.
// Staging via global_load_lds width=16 into LINEAR [128][32] LDS.
// BANK-CONFLICT SWIZZLE (both-sides-or-neither): DMA dest linear, 16B
// chunk-within-row permuted on the GLOBAL SOURCE (c_src = c_dest ^
// ((row>>1)&3)); same XOR on ds_read. All 8 bank-quads hit 2x per 16 lanes.
// MODES:
//  0: f32 store C1[row*ldc+col]                       (out_proj)
//  2: split in_proj: col<D_INNER -> f32 C1; else bf16 C2@col-2048
//  3: split-K partials: K arg = Kc; A,B advanced by kz*Kc;
//     store f32 at C1 + kz*NTOK*DBC_N                  (dbc)
//  4: softplus(acc + bias[col]) -> f32 C1              (delta)
// ---------------------------------------------------------------------------
template<int MODE>
__global__ __launch_bounds__(256)
void mfma_gemm(int K,
               const u16* __restrict__ A, int lda,
               const u16* __restrict__ B, int ldb,   // [N][K]
               void* __restrict__ C1, int ldc,
               u16*  __restrict__ C2,
               const float* __restrict__ bias)
{
  __shared__ u16 As[128*32];
  __shared__ u16 Bs[128*32];
  const int tid  = threadIdx.x;
  const int lane = tid & 63;
  const int wave = tid >> 6;
  const int wm = (wave>>1)*64, wn = (wave&1)*64;
  const int m0 = blockIdx.y*128, n0 = blockIdx.x*128;
  const size_t koff = (MODE==3) ? (size_t)blockIdx.z*K : 0;

  const int srow = tid >> 2;        // 0..63 (row within 64-row half-tile)
  // swizzled source chunk: logical chunk stored at dest chunk (tid&3)
  const int scs  = (((tid & 3) ^ ((srow >> 1) & 3)) * 8);

  const u16* Ag = A + (size_t)(m0 + srow)*lda + scs + koff;
  const u16* Bg = B + (size_t)(n0 + srow)*ldb + scs + koff;

  const int fr = lane & 15;         // fragment row within 16
  const int fq = lane >> 4;         // quad: k-chunk of 8
  const int sx = (fr >> 1) & 3;     // read-side XOR (loop-invariant)
  const int rdoff = ((fq ^ sx) * 8);
  f32x4 acc[4][4] = {};

  u16* as0 = &As[tid*8];
  u16* as1 = &As[2048 + tid*8];
  u16* bs0 = &Bs[tid*8];
  u16* bs1 = &Bs[2048 + tid*8];

  for (int k0=0; k0<K; k0+=32){
    GLOAD_LDS16(Ag + k0,                    as0);
    GLOAD_LDS16(Ag + (size_t)64*lda + k0,   as1);
    GLOAD_LDS16(Bg + k0,                    bs0);
    GLOAD_LDS16(Bg + (size_t)64*ldb + k0,   bs1);
    __syncthreads();                 // drains vmcnt -> LDS tile ready

    bf16x8 af[4], bfr[4];
    #pragma unroll
    for (int i=0;i<4;i++){
      af[i]  = *(const bf16x8*)&As[(wm + i*16 + fr)*32 + rdoff];
      bfr[i] = *(const bf16x8*)&Bs[(wn + i*16 + fr)*32 + rdoff];
    }
    #pragma unroll
    for (int mi=0;mi<4;mi++)
      #pragma unroll
      for (int ni=0;ni<4;ni++)
        acc[mi][ni] = __builtin_amdgcn_mfma_f32_16x16x32_bf16(
            af[mi], bfr[ni], acc[mi][ni], 0, 0, 0);
    __syncthreads();                 // all reads done before next overwrite
  }

  float* Cf = (float*)C1;
  if (MODE==3) Cf += (size_t)blockIdx.z*((size_t)NTOK*DBC_N);

  // C/D layout: row = fq*4 + r, col = fr  (m89-verified)
  const bool second = (MODE==2) && (n0 >= D_INNER);   // block-uniform
  #pragma unroll
  for (int mi=0;mi<4;mi++){
    #pragma unroll
    for (int ni=0;ni<4;ni++){
      int col = n0 + wn + ni*16 + fr;
      #pragma unroll
      for (int r=0;r<4;r++){
        int row = m0 + wm + mi*16 + fq*4 + r;
        float v = acc[mi][ni][r];
        if (MODE==0 || MODE==3){
          Cf[(size_t)row*ldc + col] = v;
        } else if (MODE==4){
          v += bias[col];
          v = (v > 20.f) ? v : log1pf(__expf(v));
          Cf[(size_t)row*ldc + col] = v;
        } else {  // MODE 2
          if (second) C2[(size_t)row*D_INNER + (col - D_INNER)] = f2bf(v);
          else        Cf[(size_t)row*D_INNER + col] = v;
        }
      }
    }
  }
}

// ---------------------------------------------------------------------------
// f32 -> bf16 elementwise (n multiple of 1024)
// ---------------------------------------------------------------------------
__global__ __launch_bounds__(256)
void cvt_f32_bf16(const float* __restrict__ in, u16* __restrict__ out)
{
  size_t i = (size_t)blockIdx.x*256 + threadIdx.x;
  float4 v = ((const float4*)in)[i];
  ushort4 o;
  o.x=f2bf(v.x); o.y=f2bf(v.y); o.z=f2bf(v.z); o.w=f2bf(v.w);
  ((ushort4*)out)[i] = o;
}

// ---------------------------------------------------------------------------
// f32 [R][C] -> bf16 [C][R] transpose+convert, 64x64 tiles, 256 threads.
// ---------------------------------------------------------------------------
__global__ __launch_bounds__(256)
void transpose_cvt(const float* __restrict__ in, u16* __restrict__ out,
                   int R, int C)
{
  __shared__ float tile[64][65];
  const int bc = blockIdx.x*64, br = blockIdx.y*64;
  const int tx = threadIdx.x & 63, ty = threadIdx.x >> 6;
  #pragma unroll
  for (int i=0;i<16;i++){
    int r = ty + i*4;
    tile[r][tx] = in[(size_t)(br+r)*C + bc+tx];
  }
  __syncthreads();
  #pragma unroll
  for (int i=0;i<16;i++){
    int r = ty + i*4;
    out[(size_t)(bc+r)*R + br+tx] = f2bf(tile[tx][r]);
  }
}

// ---------------------------------------------------------------------------
// reduce KSPLIT partials into dbc (float4-vectorized over NTOK*DBC_N).
// Also emits the dt columns (col<64) as bf16 [NTOK][64] for the delta MFMA.
// ---------------------------------------------------------------------------
__global__ __launch_bounds__(256)
void reduce_pk(const float* __restrict__ part, float* __restrict__ dbc,
               u16* __restrict__ dtbf)
{
  size_t i = (size_t)blockIdx.x*256 + threadIdx.x;   // float4 index
  const size_t stride4 = (size_t)NTOK*DBC_N/4;
  float4 s = ((const float4*)part)[i];
  #pragma unroll
  for (int z=1; z<KSPLIT; ++z){
    float4 v = ((const float4*)part)[z*stride4 + i];
    s.x+=v.x; s.y+=v.y; s.z+=v.z; s.w+=v.w;
  }
  ((float4*)dbc)[i] = s;
  int j = (int)(i & 31);               // float4 index within a 128-col row
  if (j < 16){                          // cols 0..63 = dt
    size_t row = i >> 5;
    ushort4 o;
    o.x=f2bf(s.x); o.y=f2bf(s.y); o.z=f2bf(s.z); o.w=f2bf(s.w);
    *(ushort4*)(dtbf + row*DT_RANK + 4*j) = o;
  }
}

// ---------------------------------------------------------------------------
// Depthwise causal conv (K=4) + bias + SiLU. xi_raw (f32, ld 2048) ->
// xi_post f32 (scan u) + xi_bf bf16 (dbc-GEMM A operand).
// ---------------------------------------------------------------------------
__global__ __launch_bounds__(256)
void conv_silu_kernel(const float* __restrict__ xi_raw,
                      const float* __restrict__ conv_w,
                      const float* __restrict__ conv_b,
                      float* __restrict__ xi_post,
                      u16*   __restrict__ xi_bf)
{
  size_t idx = (size_t)blockIdx.x*256 + threadIdx.x;   // over NTOK*D_INNER
  int d = (int)(idx % D_INNER);
  size_t bt = idx / D_INNER;
  int t = (int)(bt % SEQ);
  size_t b = bt / SEQ;
  const float* xi = xi_raw + b*(size_t)SEQ*D_INNER;
  float accv = conv_b[d];
  #pragma unroll
  for (int k=0;k<D_CONV;k++){
    int tt = t + k - (D_CONV-1);
    if (tt >= 0) accv += xi[(size_t)tt*D_INNER + d] * conv_w[d*D_CONV + k];
  }
  float res = accv * sigmoidf_(accv);
  xi_post[idx] = res;
  xi_bf[idx]   = f2bf(res);
}

// ---------------------------------------------------------------------------
// Chunked selective scan, pass 1: lane = channel, h[32] in registers.
// FAST PATH (runtime-verified): A_log = log(tile(arange(1..32))) ->
// A2[s] = A2[0]*(s+1), so exp(dl*A[s]) = E^(s+1): ONE v_exp per timestep.
// ---------------------------------------------------------------------------
__global__ __launch_bounds__(256)
void scan_part1(const float* __restrict__ dbc,     // (NTOK,128)
                const float* __restrict__ delta,   // (NTOK,D_INNER)
                const float* __restrict__ u,       // (NTOK,D_INNER)
                const float* __restrict__ A_log,   // (D_INNER,32)
                float* __restrict__ q,             // (B,NC,D_INNER,32)
                float* __restrict__ sumdl_buf)     // (B,NC,D_INNER)
{
  const int ndg  = D_INNER/256;                 // 8
  const int dgrp = blockIdx.x % ndg;
  const int c    = (blockIdx.x / ndg) % NC;
  const int b    =  blockIdx.x / (ndg*NC);
  const int d    = dgrp*256 + threadIdx.x;

  const float* Ap = A_log + (size_t)d*D_STATE;
  const float base = -__expf(Ap[0]) * LOG2E;      // log2e folded into A
  bool fastp = true;
  #pragma unroll
  for (int s=1; s<D_STATE; ++s){
    float a2 = -__expf(Ap[s]) * LOG2E;
    float ideal = base * (float)(s+1);
    fastp = fastp && (fabsf(a2 - ideal) <= 1e-4f*fabsf(ideal));
  }

  const size_t tok0 = (size_t)b*SEQ + (size_t)c*CL;
  const float* dptr = delta + tok0*D_INNER + d;
  const float* uptr = u     + tok0*D_INNER + d;
  const float* dbcp = dbc   + tok0*DBC_N;

  float h[D_STATE] = {};
  float sumdl = 0.f;

  if (fastp){
    for (int t=0; t<CL; ++t){
      float dl = dptr[(size_t)t*D_INNER];
      float uu = uptr[(size_t)t*D_INNER];
      sumdl += dl;
      float w  = dl*uu;
      float E  = exp2_fast(dl*base);
      float E2 = E*E, E3 = E2*E, E4 = E2*E2;
      float P  = 1.f;
      const float4* B4 = (const float4*)(dbcp + (size_t)t*DBC_N + DT_RANK);
      #pragma unroll
      for (int g=0; g<8; ++g){
        float4 Bv = B4[g];
        float m0 = P*E, m1 = P*E2, m2 = P*E3, m3 = P*E4;
        h[4*g+0] = m0*h[4*g+0] + w*Bv.x;
        h[4*g+1] = m1*h[4*g+1] + w*Bv.y;
        h[4*g+2] = m2*h[4*g+2] + w*Bv.z;
        h[4*g+3] = m3*h[4*g+3] + w*Bv.w;
        P = m3;
      }
    }
  } else {
    float A2[D_STATE];
    #pragma unroll
    for (int g=0; g<8; ++g){
      float4 al = *(const float4*)(Ap + 4*g);
      A2[4*g+0] = -__expf(al.x)*LOG2E; A2[4*g+1] = -__expf(al.y)*LOG2E;
      A2[4*g+2] = -__expf(al.z)*LOG2E; A2[4*g+3] = -__expf(al.w)*LOG2E;
    }
    for (int t=0; t<CL; ++t){
      float dl = dptr[(size_t)t*D_INNER];
      float uu = uptr[(size_t)t*D_INNER];
      sumdl += dl;
      float w = dl*uu;
      const float4* B4 = (const float4*)(dbcp + (size_t)t*DBC_N + DT_RANK);
      #pragma unroll
      for (int g=0; g<8; ++g){
        float4 Bv = B4[g];
        h[4*g+0] = exp2_fast(dl*A2[4*g+0])*h[4*g+0] + w*Bv.x;
        h[4*g+1] = exp2_fast(dl*A2[4*g+1])*h[4*g+1] + w*Bv.y;
        h[4*g+2] = exp2_fast(dl*A2[4*g+2])*h[4*g+2] + w*Bv.z;
        h[4*g+3] = exp2_fast(dl*A2[4*g+3])*h[4*g+3] + w*Bv.w;
      }
    }
  }

  float* qp = q + (((size_t)b*NC + c)*D_INNER + d)*D_STATE;
  #pragma unroll
  for (int g=0; g<8; ++g)
    ((float4*)qp)[g] = make_float4(h[4*g+0],h[4*g+1],h[4*g+2],h[4*g+3]);
  sumdl_buf[((size_t)b*NC + c)*D_INNER + d] = sumdl;
}

// ---------------------------------------------------------------------------
// Pass 2: sequential combine across chunks, in-place on q.
// ---------------------------------------------------------------------------
__global__ __launch_bounds__(256)
void scan_combine(float* __restrict__ q,
                  const float* __restrict__ sumdl_buf,
                  const float* __restrict__ A_log)
{
  size_t idx = (size_t)blockIdx.x*256 + threadIdx.x;   // over B*D_INNER*32
  int s = (int)(idx % D_STATE);
  size_t dd = idx / D_STATE;
  int d = (int)(dd % D_INNER);
  int b = (int)(dd / D_INNER);

  const float As2 = -__expf(A_log[(size_t)d*D_STATE + s]) * LOG2E;
  float H = 0.f;
  for (int c=0; c<NC; ++c){
    size_t off = (((size_t)b*NC + c)*D_INNER + d)*D_STATE + s;
    float tmp = q[off];          // chunk-local end state
    q[off] = H;                  // h_in for chunk c
    H = exp2_fast(As2 * sumdl_buf[((size_t)b*NC + c)*D_INNER + d]) * H + tmp;
  }
}

// ---------------------------------------------------------------------------
// Pass 3: re-run recurrence from h_in; y = sum_s h*C, fused D-skip + z-gate.
// z bf16 read, y bf16 written IN-PLACE (same slot, same thread -> race-free).
// ---------------------------------------------------------------------------
__global__ __launch_bounds__(256)
void scan_part2(const float* __restrict__ dbc,     // (NTOK,128)
                const float* __restrict__ delta,   // (NTOK,D_INNER)
                const float* __restrict__ u,
                u16*         __restrict__ zy,      // in: z bf16, out: y bf16
                const float* __restrict__ q,       // h_in per chunk
                const float* __restrict__ A_log,
                const float* __restrict__ Dp)
{
  const int ndg  = D_INNER/256;
  const int dgrp = blockIdx.x % ndg;
  const int c    = (blockIdx.x / ndg) % NC;
  const int b    =  blockIdx.x / (ndg*NC);
  const int d    = dgrp*256 + threadIdx.x;

  const float* Ap = A_log + (size_t)d*D_STATE;
  const float base = -__expf(Ap[0]) * LOG2E;
  bool fastp = true;
  #pragma unroll
  for (int s=1; s<D_STATE; ++s){
    float a2 = -__expf(Ap[s]) * LOG2E;
    float ideal = base * (float)(s+1);
    fastp = fastp && (fabsf(a2 - ideal) <= 1e-4f*fabsf(ideal));
  }

  float h[D_STATE];
  const float* qp = q + (((size_t)b*NC + c)*D_INNER + d)*D_STATE;
  #pragma unroll
  for (int g=0; g<8; ++g){
    float4 hv = ((const float4*)qp)[g];
    h[4*g+0]=hv.x; h[4*g+1]=hv.y; h[4*g+2]=hv.z; h[4*g+3]=hv.w;
  }
  const float Dd = Dp[d];

  const size_t tok0 = (size_t)b*SEQ + (size_t)c*CL;
  const float* dptr = delta + tok0*D_INNER + d;
  const float* uptr = u     + tok0*D_INNER + d;
  u16*         zp   = zy    + tok0*D_INNER + d;
  const float* dbcp = dbc   + tok0*DBC_N;

  if (fastp){
    for (int t=0; t<CL; ++t){
      float dl = dptr[(size_t)t*D_INNER];
      float uu = uptr[(size_t)t*D_INNER];
      float zz = bf2f(zp[(size_t)t*D_INNER]);
      float w  = dl*uu;
      float E  = exp2_fast(dl*base);
      float E2 = E*E, E3 = E2*E, E4 = E2*E2;
      float P  = 1.f;
      const float4* B4 = (const float4*)(dbcp + (size_t)t*DBC_N + DT_RANK);
      const float4* C4 = B4 + 8;
      float y = 0.f;
      #pragma unroll
      for (int g=0; g<8; ++g){
        float4 Bv = B4[g];
        float4 Cv = C4[g];
        float m0 = P*E, m1 = P*E2, m2 = P*E3, m3 = P*E4;
        h[4*g+0] = m0*h[4*g+0] + w*Bv.x;  y += h[4*g+0]*Cv.x;
        h[4*g+1] = m1*h[4*g+1] + w*Bv.y;  y += h[4*g+1]*Cv.y;
        h[4*g+2] = m2*h[4*g+2] + w*Bv.z;  y += h[4*g+2]*Cv.z;
        h[4*g+3] = m3*h[4*g+3] + w*Bv.w;  y += h[4*g+3]*Cv.w;
        P = m3;
      }
      zp[(size_t)t*D_INNER] = f2bf((y + uu*Dd) * (zz * sigmoidf_(zz)));
    }
  } else {
    float A2[D_STATE];
    #pragma unroll
    for (int g=0; g<8; ++g){
      float4 al = *(const float4*)(Ap + 4*g);
      A2[4*g+0] = -__expf(al.x)*LOG2E; A2[4*g+1] = -__expf(al.y)*LOG2E;
      A2[4*g+2] = -__expf(al.z)*LOG2E; A2[4*g+3] = -__expf(al.w)*LOG2E;
    }
    for (int t=0; t<CL; ++t){
      float dl = dptr[(size_t)t*D_INNER];
      float uu = uptr[(size_t)t*D_INNER];
      float zz = bf2f(zp[(size_t)t*D_INNER]);
      float w  = dl*uu;
      const float4* B4 = (const float4*)(dbcp + (size_t)t*DBC_N + DT_RANK);
      const float4* C4 = B4 + 8;
      float y = 0.f;
      #pragma unroll
      for (int g=0; g<8; ++g){
        float4 Bv = B4[g];
        float4 Cv = C4[g];
        h[4*g+0] = exp2_fast(dl*A2[4*g+0])*h[4*g+0] + w*Bv.x;  y += h[4*g+0]*Cv.x;
        h[4*g+1] = exp2_fast(dl*A2[4*g+1])*h[4*g+1] + w*Bv.y;  y += h[4*g+1]*Cv.y;
        h[4*g+2] = exp2_fast(dl*A2[4*g+2])*h[4*g+2] + w*Bv.z;  y += h[4*g+2]*Cv.z;
        h[4*g+3] = exp2_fast(dl*A2[4*g+3])*h[4*g+3] + w*Bv.w;  y += h[4*g+3]*Cv.w;
      }
      zp[(size_t)t*D_INNER] = f2bf((y + uu*Dd) * (zz * sigmoidf_(zz)));
    }
  }
}

// ---------------------------------------------------------------------------
// LayerNorm over last dim (1024): read f32 pre-LN, write f32 output.
// ---------------------------------------------------------------------------
__global__ __launch_bounds__(256)
void ln_kernel(const float* __restrict__ in,
               float* __restrict__ out,
               const float* __restrict__ gamma,
               const float* __restrict__ beta)
{
  const int row = blockIdx.x;
  const float* p = in + (size_t)row*D_MODEL;
  float* q = out + (size_t)row*D_MODEL;
  float v[4]; float s=0.f, ss=0.f;
  #pragma unroll
  for (int i=0;i<4;i++){
    float x = p[i*256 + threadIdx.x];
    v[i]=x; s+=x; ss+=x*x;
  }
  #pragma unroll
  for (int off=32; off; off>>=1){
    s  += __shfl_xor(s,  off, 64);
    ss += __shfl_xor(ss, off, 64);
  }
  __shared__ float sw[4], ssw[4];
  const int wid = threadIdx.x >> 6;
  if ((threadIdx.x & 63) == 0){ sw[wid]=s; ssw[wid]=ss; }
  __syncthreads();
  s  = sw[0]+sw[1]+sw[2]+sw[3];
  ss = ssw[0]+ssw[1]+ssw[2]+ssw[3];
  const float mu  = s * (1.f/D_MODEL);
  const float var = ss * (1.f/D_MODEL) - mu*mu;
  const float inv = rsqrtf(var + 1e-5f);
  #pragma unroll
  for (int i=0;i<4;i++){
    int col = i*256 + threadIdx.x;
    q[col] = (v[i]-mu)*inv*gamma[col] + beta[col];
  }
}

// ---------------------------------------------------------------------------
extern "C" void kernel_launch(void* const* d_in, const int* in_sizes, int n_in,
                              void* d_out, int out_size, void* d_ws, size_t ws_size,
                              hipStream_t stream)
{
  const float* x          = (const float*)d_in[0];   // (4,2048,1024) f32
  const float* in_proj_w  = (const float*)d_in[1];   // (1024,4096)
  const float* conv_w     = (const float*)d_in[2];   // (2048,4)
  const float* conv_b     = (const float*)d_in[3];   // (2048,)
  const float* x_proj_w   = (const float*)d_in[4];   // (2048,128)
  const float* dt_proj_w  = (const float*)d_in[5];   // (64,2048)
  const float* dt_proj_b  = (const float*)d_in[6];   // (2048,)
  const float* A_log      = (const float*)d_in[7];   // (2048,32)
  const float* Dp         = (const float*)d_in[8];   // (2048,)
  const float* out_proj_w = (const float*)d_in[9];   // (2048,1024)
  const float* ln_gamma   = (const float*)d_in[10];  // (1024,)
  const float* ln_beta    = (const float*)d_in[11];  // (1024,)
  float* out = (float*)d_out;                        // (4,2048,1024) f32 OUTPUT

  // workspace (MiB offsets), ws_size = 256 MiB:
  //   @0    xi_raw f32 64M -> pkpart f32 32M (dbc split-K) -> delta f32 -> preln
  //   @64   xi_post f32 64M
  //   @128  z bf16 32M -> y bf16 (in-place)
  //   @160  x_bf 16M (prep only) / dbc f32 4M (after x_bf dead)
  //   @164  xi_bf bf16 32M [164,196)  (dead before qbuf written)
  //   @164  qbuf f32 64M  [164,228)   (scan only)
  //   @228  sumdl f32 2M  [228,230)
  //   @230  w_inT bf16 8M [230,238)
  //   @238  w_outT bf16 4M [238,242)
  //   @242  x_projT bf16 512K ; @242.5 dt_projT bf16 256K ; @243 dtbf bf16 1M
  char* ws = (char*)d_ws;
  float* xi_raw  = (float*)(ws + 0);
  float* pkpart  = (float*)(ws + 0);
  float* deltab  = (float*)(ws + 0);
  float* preln   = (float*)(ws + 0);
  float* xi_post = (float*)(ws + (size_t) 67108864);
  u16*   zybuf   = (u16*)  (ws + (size_t)134217728);
  u16*   x_bf    = (u16*)  (ws + (size_t)167772160);
  float* dbc     = (float*)(ws + (size_t)167772160);
  u16*   xi_bf   = (u16*)  (ws + (size_t)171966464);
  float* qbuf    = (float*)(ws + (size_t)171966464);
  float* sumdl   = (float*)(ws + (size_t)239075328);
  u16*   w_inT   = (u16*)  (ws + (size_t)241172480);
  u16*   w_outT  = (u16*)  (ws + (size_t)249561088);
  u16*   x_projT = (u16*)  (ws + (size_t)253755392);
  u16*   dt_projT= (u16*)  (ws + (size_t)254279680);
  u16*   dtbf    = (u16*)  (ws + (size_t)254803968);

  // 0) dtype prep: x -> bf16; weights -> bf16 transposed [N][K]
  cvt_f32_bf16<<<(NTOK*(size_t)D_MODEL)/1024, 256, 0, stream>>>(x, x_bf);
  { dim3 g(4096/64, 1024/64); transpose_cvt<<<g,256,0,stream>>>(in_proj_w,  w_inT,  1024, 4096); }
  { dim3 g(1024/64, 2048/64); transpose_cvt<<<g,256,0,stream>>>(out_proj_w, w_outT, 2048, 1024); }
  { dim3 g( 128/64, 2048/64); transpose_cvt<<<g,256,0,stream>>>(x_proj_w,   x_projT, 2048, 128); }
  { dim3 g(2048/64,   64/64); transpose_cvt<<<g,256,0,stream>>>(dt_proj_w,  dt_projT,  64, 2048); }

  // 1) merged in_proj: [xi | z] = x @ in_proj_w  (MFMA, split epilogue)
  {
    dim3 grid(2*D_INNER/128, NTOK/128);
    mfma_gemm<2><<<grid,256,0,stream>>>(D_MODEL,
        x_bf, D_MODEL, w_inT, D_MODEL, xi_raw, 0, zybuf, nullptr);
  }
  // 2) xi_post(f32) + xi_bf(bf16) = silu(conv(xi_raw) + conv_b)
  conv_silu_kernel<<<(NTOK*(size_t)D_INNER)/256,256,0,stream>>>(
      xi_raw, conv_w, conv_b, xi_post, xi_bf);

  // 3) dbc = xi_bf @ x_proj_w  (MFMA split-K over 8, partials in pkpart @0,
  //    xi_raw dead). reduce also emits dt cols as bf16 for step 4.
  {
    dim3 grid(DBC_N/128, NTOK/128, KSPLIT);     // (1,64,8)
    mfma_gemm<3><<<grid,256,0,stream>>>(D_INNER/KSPLIT,
        xi_bf, D_INNER, x_projT, D_INNER, pkpart, DBC_N, nullptr, nullptr);
    reduce_pk<<<(NTOK*(size_t)DBC_N)/1024,256,0,stream>>>(pkpart, dbc, dtbf);
  }
  // 4) delta = softplus(dtbf @ dt_proj_w + b)  (MFMA, K=64) -> @0
  {
    dim3 grid(D_INNER/128, NTOK/128);
    mfma_gemm<4><<<grid,256,0,stream>>>(DT_RANK,
        dtbf, DT_RANK, dt_projT, DT_RANK, deltab, D_INNER, nullptr, dt_proj_b);
  }
  // 5) chunked scan (NC=64); part2 writes y bf16 in-place over z
  {
    dim3 grid1((D_INNER/256)*NC*BATCH);           // 2048 blocks
    scan_part1<<<grid1,256,0,stream>>>(dbc, deltab, xi_post, A_log, qbuf, sumdl);
    scan_combine<<<(BATCH*(size_t)D_INNER*D_STATE)/256,256,0,stream>>>(qbuf, sumdl, A_log);
    scan_part2<<<grid1,256,0,stream>>>(dbc, deltab, xi_post, zybuf, qbuf, A_log, Dp);
  }
  // 6) preln = y @ out_proj_w              (MFMA, f32 out) -> @0
  {
    dim3 grid(D_MODEL/128, NTOK/128);
    mfma_gemm<0><<<grid,256,0,stream>>>(D_INNER,
        zybuf, D_INNER, w_outT, D_INNER, preln, D_MODEL, nullptr, nullptr);
  }
  // 7) LayerNorm: preln f32 -> out f32
  ln_kernel<<<NTOK,256,0,stream>>>(preln, out, ln_gamma, ln_beta);
}

// Round 4
// 588.710 us; speedup vs baseline: 1.2775x; 1.0583x over previous
//
#include <hip/hip_runtime.h>
#include <math.h>

#define D_MODEL 1024
#define D_STATE 32
#define D_CONV  4
#define D_INNER 2048
#define DT_RANK 64
#define BATCH   4
#define SEQ     2048
#define NTOK    (BATCH*SEQ)            // 8192 rows
#define DBC_N   (DT_RANK + 2*D_STATE)  // 128
#define NC      32                     // scan chunks
#define CL      (SEQ/NC)               // 64 steps per chunk
#define KSPLIT  8                      // split-K factor for dbc GEMM
#define LOG2E   1.4426950408889634f

typedef unsigned short u16;
typedef short bf16x8 __attribute__((ext_vector_type(8)));
typedef float f32x4  __attribute__((ext_vector_type(4)));

__device__ __forceinline__ float bf2f(u16 u){
  return __uint_as_float(((unsigned)u) << 16);
}
__device__ __forceinline__ u16 f2bf(float f){   // round-to-nearest-even
  unsigned u = __float_as_uint(f);
  return (u16)((u + 0x7fffu + ((u >> 16) & 1u)) >> 16);
}
__device__ __forceinline__ float sigmoidf_(float x){ return 1.f/(1.f+__expf(-x)); }
// raw v_exp_f32: r = 2^x (1 instruction; __expf = mul + this)
__device__ __forceinline__ float exp2_fast(float x){
  float r;
  asm("v_exp_f32 %0, %1" : "=v"(r) : "v"(x));
  return r;
}

typedef __attribute__((address_space(3))) void       lds_v;
typedef const __attribute__((address_space(1))) void gl_v;
#define GLOAD_LDS16(g, l) \
  __builtin_amdgcn_global_load_lds((gl_v*)(g), (lds_v*)(l), 16, 0, 0)

// ---------------------------------------------------------------------------
// bf16 MFMA GEMM: C = A[M,K] @ W[K,N], A bf16 row-major [M][K], B = weight
// PRE-TRANSPOSED bf16 [N][K]. 128x128 tile, BK=32, 4 waves of 64x64.
// Staging via global_load_lds width=16 into LINEAR [128][32] LDS.
// BANK-CONFLICT SWIZZLE (both-sides-or-neither): DMA dest linear, 16B
// chunk-within-row permuted on the GLOBAL SOURCE (c_src = c_dest ^
// ((row>>1)&3)); same XOR on ds_read. All 8 bank-quads hit 2x per 16 lanes.
// MODES:
//  0: f32 store C1[row*ldc+col]                       (out_proj)
//  2: split in_proj, BOTH bf16: col<D_INNER -> (u16*)C1; else C2@col-2048
//  3: split-K partials: K arg = Kc; A,B advanced by kz*Kc;
//     store f32 at C1 + kz*NTOK*DBC_N                  (dbc)
//  4: softplus(acc + bias[col]) -> bf16 C1             (delta)
// ---------------------------------------------------------------------------
template<int MODE>
__global__ __launch_bounds__(256)
void mfma_gemm(int K,
               const u16* __restrict__ A, int lda,
               const u16* __restrict__ B, int ldb,   // [N][K]
               void* __restrict__ C1, int ldc,
               u16*  __restrict__ C2,
               const float* __restrict__ bias)
{
  __shared__ u16 As[128*32];
  __shared__ u16 Bs[128*32];
  const int tid  = threadIdx.x;
  const int lane = tid & 63;
  const int wave = tid >> 6;
  const int wm = (wave>>1)*64, wn = (wave&1)*64;
  const int m0 = blockIdx.y*128, n0 = blockIdx.x*128;
  const size_t koff = (MODE==3) ? (size_t)blockIdx.z*K : 0;

  const int srow = tid >> 2;        // 0..63 (row within 64-row half-tile)
  // swizzled source chunk: logical chunk stored at dest chunk (tid&3)
  const int scs  = (((tid & 3) ^ ((srow >> 1) & 3)) * 8);

  const u16* Ag = A + (size_t)(m0 + srow)*lda + scs + koff;
  const u16* Bg = B + (size_t)(n0 + srow)*ldb + scs + koff;

  const int fr = lane & 15;         // fragment row within 16
  const int fq = lane >> 4;         // quad: k-chunk of 8
  const int sx = (fr >> 1) & 3;     // read-side XOR (loop-invariant)
  const int rdoff = ((fq ^ sx) * 8);
  f32x4 acc[4][4] = {};

  u16* as0 = &As[tid*8];
  u16* as1 = &As[2048 + tid*8];
  u16* bs0 = &Bs[tid*8];
  u16* bs1 = &Bs[2048 + tid*8];

  for (int k0=0; k0<K; k0+=32){
    GLOAD_LDS16(Ag + k0,                    as0);
    GLOAD_LDS16(Ag + (size_t)64*lda + k0,   as1);
    GLOAD_LDS16(Bg + k0,                    bs0);
    GLOAD_LDS16(Bg + (size_t)64*ldb + k0,   bs1);
    __syncthreads();                 // drains vmcnt -> LDS tile ready

    bf16x8 af[4], bfr[4];
    #pragma unroll
    for (int i=0;i<4;i++){
      af[i]  = *(const bf16x8*)&As[(wm + i*16 + fr)*32 + rdoff];
      bfr[i] = *(const bf16x8*)&Bs[(wn + i*16 + fr)*32 + rdoff];
    }
    #pragma unroll
    for (int mi=0;mi<4;mi++)
      #pragma unroll
      for (int ni=0;ni<4;ni++)
        acc[mi][ni] = __builtin_amdgcn_mfma_f32_16x16x32_bf16(
            af[mi], bfr[ni], acc[mi][ni], 0, 0, 0);
    __syncthreads();                 // all reads done before next overwrite
  }

  float* Cf = (float*)C1;
  if (MODE==3) Cf += (size_t)blockIdx.z*((size_t)NTOK*DBC_N);

  // C/D layout: row = fq*4 + r, col = fr  (m89-verified)
  const bool second = (MODE==2) && (n0 >= D_INNER);   // block-uniform
  #pragma unroll
  for (int mi=0;mi<4;mi++){
    #pragma unroll
    for (int ni=0;ni<4;ni++){
      int col = n0 + wn + ni*16 + fr;
      #pragma unroll
      for (int r=0;r<4;r++){
        int row = m0 + wm + mi*16 + fq*4 + r;
        float v = acc[mi][ni][r];
        if (MODE==0 || MODE==3){
          Cf[(size_t)row*ldc + col] = v;
        } else if (MODE==4){
          v += bias[col];
          v = (v > 20.f) ? v : log1pf(__expf(v));
          ((u16*)C1)[(size_t)row*ldc + col] = f2bf(v);
        } else {  // MODE 2: dual bf16
          if (second) C2[(size_t)row*D_INNER + (col - D_INNER)] = f2bf(v);
          else        ((u16*)C1)[(size_t)row*D_INNER + col]     = f2bf(v);
        }
      }
    }
  }
}

// ---------------------------------------------------------------------------
// f32 -> bf16 elementwise (n multiple of 1024)
// ---------------------------------------------------------------------------
__global__ __launch_bounds__(256)
void cvt_f32_bf16(const float* __restrict__ in, u16* __restrict__ out)
{
  size_t i = (size_t)blockIdx.x*256 + threadIdx.x;
  float4 v = ((const float4*)in)[i];
  ushort4 o;
  o.x=f2bf(v.x); o.y=f2bf(v.y); o.z=f2bf(v.z); o.w=f2bf(v.w);
  ((ushort4*)out)[i] = o;
}

// ---------------------------------------------------------------------------
// f32 [R][C] -> bf16 [C][R] transpose+convert, 64x64 tiles, 256 threads.
// ---------------------------------------------------------------------------
__global__ __launch_bounds__(256)
void transpose_cvt(const float* __restrict__ in, u16* __restrict__ out,
                   int R, int C)
{
  __shared__ float tile[64][65];
  const int bc = blockIdx.x*64, br = blockIdx.y*64;
  const int tx = threadIdx.x & 63, ty = threadIdx.x >> 6;
  #pragma unroll
  for (int i=0;i<16;i++){
    int r = ty + i*4;
    tile[r][tx] = in[(size_t)(br+r)*C + bc+tx];
  }
  __syncthreads();
  #pragma unroll
  for (int i=0;i<16;i++){
    int r = ty + i*4;
    out[(size_t)(bc+r)*R + br+tx] = f2bf(tile[tx][r]);
  }
}

// ---------------------------------------------------------------------------
// reduce KSPLIT partials into dbc (float4-vectorized over NTOK*DBC_N).
// Also emits the dt columns (col<64) as bf16 [NTOK][64] for the delta MFMA.
// ---------------------------------------------------------------------------
__global__ __launch_bounds__(256)
void reduce_pk(const float* __restrict__ part, float* __restrict__ dbc,
               u16* __restrict__ dtbf)
{
  size_t i = (size_t)blockIdx.x*256 + threadIdx.x;   // float4 index
  const size_t stride4 = (size_t)NTOK*DBC_N/4;
  float4 s = ((const float4*)part)[i];
  #pragma unroll
  for (int z=1; z<KSPLIT; ++z){
    float4 v = ((const float4*)part)[z*stride4 + i];
    s.x+=v.x; s.y+=v.y; s.z+=v.z; s.w+=v.w;
  }
  ((float4*)dbc)[i] = s;
  int j = (int)(i & 31);               // float4 index within a 128-col row
  if (j < 16){                          // cols 0..63 = dt
    size_t row = i >> 5;
    ushort4 o;
    o.x=f2bf(s.x); o.y=f2bf(s.y); o.z=f2bf(s.z); o.w=f2bf(s.w);
    *(ushort4*)(dtbf + row*DT_RANK + 4*j) = o;
  }
}

// ---------------------------------------------------------------------------
// Depthwise causal conv (K=4) + bias + SiLU. bf16 in -> bf16 out (u).
// ---------------------------------------------------------------------------
__global__ __launch_bounds__(256)
void conv_silu_kernel(const u16* __restrict__ xi_bf,
                      const float* __restrict__ conv_w,
                      const float* __restrict__ conv_b,
                      u16* __restrict__ u_bf)
{
  size_t idx = (size_t)blockIdx.x*256 + threadIdx.x;   // over NTOK*D_INNER
  int d = (int)(idx % D_INNER);
  size_t bt = idx / D_INNER;
  int t = (int)(bt % SEQ);
  size_t b = bt / SEQ;
  const u16* xi = xi_bf + b*(size_t)SEQ*D_INNER;
  float accv = conv_b[d];
  #pragma unroll
  for (int k=0;k<D_CONV;k++){
    int tt = t + k - (D_CONV-1);
    if (tt >= 0) accv += bf2f(xi[(size_t)tt*D_INNER + d]) * conv_w[d*D_CONV + k];
  }
  float res = accv * sigmoidf_(accv);
  u_bf[idx] = f2bf(res);
}

// ---------------------------------------------------------------------------
// Chunked selective scan, pass 1: lane = channel, h[32] in registers.
// FAST PATH (runtime-verified): A_log = log(tile(arange(1..32))) ->
// A2[s] = A2[0]*(s+1), so exp(dl*A[s]) = E^(s+1): ONE v_exp per timestep.
// delta/u are bf16.
// ---------------------------------------------------------------------------
__global__ __launch_bounds__(256)
void scan_part1(const float* __restrict__ dbc,     // (NTOK,128)
                const u16*   __restrict__ delta,   // (NTOK,D_INNER) bf16
                const u16*   __restrict__ u,       // (NTOK,D_INNER) bf16
                const float* __restrict__ A_log,   // (D_INNER,32)
                float* __restrict__ q,             // (B,NC,D_INNER,32)
                float* __restrict__ sumdl_buf)     // (B,NC,D_INNER)
{
  const int ndg  = D_INNER/256;                 // 8
  const int dgrp = blockIdx.x % ndg;
  const int c    = (blockIdx.x / ndg) % NC;
  const int b    =  blockIdx.x / (ndg*NC);
  const int d    = dgrp*256 + threadIdx.x;

  const float* Ap = A_log + (size_t)d*D_STATE;
  const float base = -__expf(Ap[0]) * LOG2E;      // log2e folded into A
  bool fastp = true;
  #pragma unroll
  for (int s=1; s<D_STATE; ++s){
    float a2 = -__expf(Ap[s]) * LOG2E;
    float ideal = base * (float)(s+1);
    fastp = fastp && (fabsf(a2 - ideal) <= 1e-4f*fabsf(ideal));
  }

  const size_t tok0 = (size_t)b*SEQ + (size_t)c*CL;
  const u16*   dptr = delta + tok0*D_INNER + d;
  const u16*   uptr = u     + tok0*D_INNER + d;
  const float* dbcp = dbc   + tok0*DBC_N;

  float h[D_STATE] = {};
  float sumdl = 0.f;

  if (fastp){
    for (int t=0; t<CL; ++t){
      float dl = bf2f(dptr[(size_t)t*D_INNER]);
      float uu = bf2f(uptr[(size_t)t*D_INNER]);
      sumdl += dl;
      float w  = dl*uu;
      float E  = exp2_fast(dl*base);
      float E2 = E*E, E3 = E2*E, E4 = E2*E2;
      float P  = 1.f;
      const float4* B4 = (const float4*)(dbcp + (size_t)t*DBC_N + DT_RANK);
      #pragma unroll
      for (int g=0; g<8; ++g){
        float4 Bv = B4[g];
        float m0 = P*E, m1 = P*E2, m2 = P*E3, m3 = P*E4;
        h[4*g+0] = m0*h[4*g+0] + w*Bv.x;
        h[4*g+1] = m1*h[4*g+1] + w*Bv.y;
        h[4*g+2] = m2*h[4*g+2] + w*Bv.z;
        h[4*g+3] = m3*h[4*g+3] + w*Bv.w;
        P = m3;
      }
    }
  } else {
    float A2[D_STATE];
    #pragma unroll
    for (int g=0; g<8; ++g){
      float4 al = *(const float4*)(Ap + 4*g);
      A2[4*g+0] = -__expf(al.x)*LOG2E; A2[4*g+1] = -__expf(al.y)*LOG2E;
      A2[4*g+2] = -__expf(al.z)*LOG2E; A2[4*g+3] = -__expf(al.w)*LOG2E;
    }
    for (int t=0; t<CL; ++t){
      float dl = bf2f(dptr[(size_t)t*D_INNER]);
      float uu = bf2f(uptr[(size_t)t*D_INNER]);
      sumdl += dl;
      float w = dl*uu;
      const float4* B4 = (const float4*)(dbcp + (size_t)t*DBC_N + DT_RANK);
      #pragma unroll
      for (int g=0; g<8; ++g){
        float4 Bv = B4[g];
        h[4*g+0] = exp2_fast(dl*A2[4*g+0])*h[4*g+0] + w*Bv.x;
        h[4*g+1] = exp2_fast(dl*A2[4*g+1])*h[4*g+1] + w*Bv.y;
        h[4*g+2] = exp2_fast(dl*A2[4*g+2])*h[4*g+2] + w*Bv.z;
        h[4*g+3] = exp2_fast(dl*A2[4*g+3])*h[4*g+3] + w*Bv.w;
      }
    }
  }

  float* qp = q + (((size_t)b*NC + c)*D_INNER + d)*D_STATE;
  #pragma unroll
  for (int g=0; g<8; ++g)
    ((float4*)qp)[g] = make_float4(h[4*g+0],h[4*g+1],h[4*g+2],h[4*g+3]);
  sumdl_buf[((size_t)b*NC + c)*D_INNER + d] = sumdl;
}

// ---------------------------------------------------------------------------
// Pass 2: sequential combine across chunks, in-place on q.
// ---------------------------------------------------------------------------
__global__ __launch_bounds__(256)
void scan_combine(float* __restrict__ q,
                  const float* __restrict__ sumdl_buf,
                  const float* __restrict__ A_log)
{
  size_t idx = (size_t)blockIdx.x*256 + threadIdx.x;   // over B*D_INNER*32
  int s = (int)(idx % D_STATE);
  size_t dd = idx / D_STATE;
  int d = (int)(dd % D_INNER);
  int b = (int)(dd / D_INNER);

  const float As2 = -__expf(A_log[(size_t)d*D_STATE + s]) * LOG2E;
  float H = 0.f;
  for (int c=0; c<NC; ++c){
    size_t off = (((size_t)b*NC + c)*D_INNER + d)*D_STATE + s;
    float tmp = q[off];          // chunk-local end state
    q[off] = H;                  // h_in for chunk c
    H = exp2_fast(As2 * sumdl_buf[((size_t)b*NC + c)*D_INNER + d]) * H + tmp;
  }
}

// ---------------------------------------------------------------------------
// Pass 3: re-run recurrence from h_in; y = sum_s h*C, fused D-skip + z-gate.
// z bf16 read, y bf16 written IN-PLACE (same slot, same thread -> race-free).
// delta/u are bf16.
// ---------------------------------------------------------------------------
__global__ __launch_bounds__(256)
void scan_part2(const float* __restrict__ dbc,     // (NTOK,128)
                const u16*   __restrict__ delta,   // (NTOK,D_INNER) bf16
                const u16*   __restrict__ u,       // bf16
                u16*         __restrict__ zy,      // in: z bf16, out: y bf16
                const float* __restrict__ q,       // h_in per chunk
                const float* __restrict__ A_log,
                const float* __restrict__ Dp)
{
  const int ndg  = D_INNER/256;
  const int dgrp = blockIdx.x % ndg;
  const int c    = (blockIdx.x / ndg) % NC;
  const int b    =  blockIdx.x / (ndg*NC);
  const int d    = dgrp*256 + threadIdx.x;

  const float* Ap = A_log + (size_t)d*D_STATE;
  const float base = -__expf(Ap[0]) * LOG2E;
  bool fastp = true;
  #pragma unroll
  for (int s=1; s<D_STATE; ++s){
    float a2 = -__expf(Ap[s]) * LOG2E;
    float ideal = base * (float)(s+1);
    fastp = fastp && (fabsf(a2 - ideal) <= 1e-4f*fabsf(ideal));
  }

  float h[D_STATE];
  const float* qp = q + (((size_t)b*NC + c)*D_INNER + d)*D_STATE;
  #pragma unroll
  for (int g=0; g<8; ++g){
    float4 hv = ((const float4*)qp)[g];
    h[4*g+0]=hv.x; h[4*g+1]=hv.y; h[4*g+2]=hv.z; h[4*g+3]=hv.w;
  }
  const float Dd = Dp[d];

  const size_t tok0 = (size_t)b*SEQ + (size_t)c*CL;
  const u16*   dptr = delta + tok0*D_INNER + d;
  const u16*   uptr = u     + tok0*D_INNER + d;
  u16*         zp   = zy    + tok0*D_INNER + d;
  const float* dbcp = dbc   + tok0*DBC_N;

  if (fastp){
    for (int t=0; t<CL; ++t){
      float dl = bf2f(dptr[(size_t)t*D_INNER]);
      float uu = bf2f(uptr[(size_t)t*D_INNER]);
      float zz = bf2f(zp[(size_t)t*D_INNER]);
      float w  = dl*uu;
      float E  = exp2_fast(dl*base);
      float E2 = E*E, E3 = E2*E, E4 = E2*E2;
      float P  = 1.f;
      const float4* B4 = (const float4*)(dbcp + (size_t)t*DBC_N + DT_RANK);
      const float4* C4 = B4 + 8;
      float y = 0.f;
      #pragma unroll
      for (int g=0; g<8; ++g){
        float4 Bv = B4[g];
        float4 Cv = C4[g];
        float m0 = P*E, m1 = P*E2, m2 = P*E3, m3 = P*E4;
        h[4*g+0] = m0*h[4*g+0] + w*Bv.x;  y += h[4*g+0]*Cv.x;
        h[4*g+1] = m1*h[4*g+1] + w*Bv.y;  y += h[4*g+1]*Cv.y;
        h[4*g+2] = m2*h[4*g+2] + w*Bv.z;  y += h[4*g+2]*Cv.z;
        h[4*g+3] = m3*h[4*g+3] + w*Bv.w;  y += h[4*g+3]*Cv.w;
        P = m3;
      }
      zp[(size_t)t*D_INNER] = f2bf((y + uu*Dd) * (zz * sigmoidf_(zz)));
    }
  } else {
    float A2[D_STATE];
    #pragma unroll
    for (int g=0; g<8; ++g){
      float4 al = *(const float4*)(Ap + 4*g);
      A2[4*g+0] = -__expf(al.x)*LOG2E; A2[4*g+1] = -__expf(al.y)*LOG2E;
      A2[4*g+2] = -__expf(al.z)*LOG2E; A2[4*g+3] = -__expf(al.w)*LOG2E;
    }
    for (int t=0; t<CL; ++t){
      float dl = bf2f(dptr[(size_t)t*D_INNER]);
      float uu = bf2f(uptr[(size_t)t*D_INNER]);
      float zz = bf2f(zp[(size_t)t*D_INNER]);
      float w  = dl*uu;
      const float4* B4 = (const float4*)(dbcp + (size_t)t*DBC_N + DT_RANK);
      const float4* C4 = B4 + 8;
      float y = 0.f;
      #pragma unroll
      for (int g=0; g<8; ++g){
        float4 Bv = B4[g];
        float4 Cv = C4[g];
        h[4*g+0] = exp2_fast(dl*A2[4*g+0])*h[4*g+0] + w*Bv.x;  y += h[4*g+0]*Cv.x;
        h[4*g+1] = exp2_fast(dl*A2[4*g+1])*h[4*g+1] + w*Bv.y;  y += h[4*g+1]*Cv.y;
        h[4*g+2] = exp2_fast(dl*A2[4*g+2])*h[4*g+2] + w*Bv.z;  y += h[4*g+2]*Cv.z;
        h[4*g+3] = exp2_fast(dl*A2[4*g+3])*h[4*g+3] + w*Bv.w;  y += h[4*g+3]*Cv.w;
      }
      zp[(size_t)t*D_INNER] = f2bf((y + uu*Dd) * (zz * sigmoidf_(zz)));
    }
  }
}

// ---------------------------------------------------------------------------
// LayerNorm over last dim (1024): read f32 pre-LN, write f32 output.
// ---------------------------------------------------------------------------
__global__ __launch_bounds__(256)
void ln_kernel(const float* __restrict__ in,
               float* __restrict__ out,
               const float* __restrict__ gamma,
               const float* __restrict__ beta)
{
  const int row = blockIdx.x;
  const float* p = in + (size_t)row*D_MODEL;
  float* q = out + (size_t)row*D_MODEL;
  float v[4]; float s=0.f, ss=0.f;
  #pragma unroll
  for (int i=0;i<4;i++){
    float x = p[i*256 + threadIdx.x];
    v[i]=x; s+=x; ss+=x*x;
  }
  #pragma unroll
  for (int off=32; off; off>>=1){
    s  += __shfl_xor(s,  off, 64);
    ss += __shfl_xor(ss, off, 64);
  }
  __shared__ float sw[4], ssw[4];
  const int wid = threadIdx.x >> 6;
  if ((threadIdx.x & 63) == 0){ sw[wid]=s; ssw[wid]=ss; }
  __syncthreads();
  s  = sw[0]+sw[1]+sw[2]+sw[3];
  ss = ssw[0]+ssw[1]+ssw[2]+ssw[3];
  const float mu  = s * (1.f/D_MODEL);
  const float var = ss * (1.f/D_MODEL) - mu*mu;
  const float inv = rsqrtf(var + 1e-5f);
  #pragma unroll
  for (int i=0;i<4;i++){
    int col = i*256 + threadIdx.x;
    q[col] = (v[i]-mu)*inv*gamma[col] + beta[col];
  }
}

// ---------------------------------------------------------------------------
extern "C" void kernel_launch(void* const* d_in, const int* in_sizes, int n_in,
                              void* d_out, int out_size, void* d_ws, size_t ws_size,
                              hipStream_t stream)
{
  const float* x          = (const float*)d_in[0];   // (4,2048,1024) f32
  const float* in_proj_w  = (const float*)d_in[1];   // (1024,4096)
  const float* conv_w     = (const float*)d_in[2];   // (2048,4)
  const float* conv_b     = (const float*)d_in[3];   // (2048,)
  const float* x_proj_w   = (const float*)d_in[4];   // (2048,128)
  const float* dt_proj_w  = (const float*)d_in[5];   // (64,2048)
  const float* dt_proj_b  = (const float*)d_in[6];   // (2048,)
  const float* A_log      = (const float*)d_in[7];   // (2048,32)
  const float* Dp         = (const float*)d_in[8];   // (2048,)
  const float* out_proj_w = (const float*)d_in[9];   // (2048,1024)
  const float* ln_gamma   = (const float*)d_in[10];  // (1024,)
  const float* ln_beta    = (const float*)d_in[11];  // (1024,)
  float* out = (float*)d_out;                        // (4,2048,1024) f32 OUTPUT

  // workspace (byte offsets), ws_size = 256 MiB:
  //   @0    x_bf bf16 16M (steps 0-1) -> pkpart f32 32M (step 3)
  //   @32M  xi_bf bf16 32M (steps 1-2) -> qbuf f32 32M (step 5)
  //   @64M  u_bf bf16 32M (steps 2,3,5)
  //   @96M  zybuf bf16 32M (steps 1,5,6)
  //   @128M delta_bf bf16 32M (steps 4,5)
  //   @160M dbc f32 4M ; @164M dtbf 1M ; @165M sumdl 1M
  //   @166M preln f32 32M (steps 6,7)
  //   @198M w_inT 8M ; @206M w_outT 4M ; @210M x_projT .5M ; @210.5M dt_projT
  char* ws = (char*)d_ws;
  u16*   x_bf    = (u16*)  (ws + 0);
  float* pkpart  = (float*)(ws + 0);
  u16*   xi_bf   = (u16*)  (ws + (size_t) 33554432);
  float* qbuf    = (float*)(ws + (size_t) 33554432);
  u16*   u_bf    = (u16*)  (ws + (size_t) 67108864);
  u16*   zybuf   = (u16*)  (ws + (size_t)100663296);
  u16*   delta_bf= (u16*)  (ws + (size_t)134217728);
  float* dbc     = (float*)(ws + (size_t)167772160);
  u16*   dtbf    = (u16*)  (ws + (size_t)171966464);
  float* sumdl   = (float*)(ws + (size_t)173015040);
  float* preln   = (float*)(ws + (size_t)174063616);
  u16*   w_inT   = (u16*)  (ws + (size_t)207618048);
  u16*   w_outT  = (u16*)  (ws + (size_t)216006656);
  u16*   x_projT = (u16*)  (ws + (size_t)220200960);
  u16*   dt_projT= (u16*)  (ws + (size_t)220725248);

  // 0) dtype prep: x -> bf16; weights -> bf16 transposed [N][K]
  cvt_f32_bf16<<<(NTOK*(size_t)D_MODEL)/1024, 256, 0, stream>>>(x, x_bf);
  { dim3 g(4096/64, 1024/64); transpose_cvt<<<g,256,0,stream>>>(in_proj_w,  w_inT,  1024, 4096); }
  { dim3 g(1024/64, 2048/64); transpose_cvt<<<g,256,0,stream>>>(out_proj_w, w_outT, 2048, 1024); }
  { dim3 g( 128/64, 2048/64); transpose_cvt<<<g,256,0,stream>>>(x_proj_w,   x_projT, 2048, 128); }
  { dim3 g(2048/64,   64/64); transpose_cvt<<<g,256,0,stream>>>(dt_proj_w,  dt_projT,  64, 2048); }

  // 1) merged in_proj: [xi | z] = x @ in_proj_w  (MFMA, dual bf16 epilogue)
  {
    dim3 grid(2*D_INNER/128, NTOK/128);
    mfma_gemm<2><<<grid,256,0,stream>>>(D_MODEL,
        x_bf, D_MODEL, w_inT, D_MODEL, xi_bf, 0, zybuf, nullptr);
  }
  // 2) u = silu(conv(xi) + conv_b)   bf16 -> bf16  (xi_bf dead after)
  conv_silu_kernel<<<(NTOK*(size_t)D_INNER)/256,256,0,stream>>>(
      xi_bf, conv_w, conv_b, u_bf);

  // 3) dbc = u_bf @ x_proj_w  (MFMA split-K over 8, partials @0, x_bf dead).
  //    reduce also emits dt cols as bf16 for step 4.
  {
    dim3 grid(DBC_N/128, NTOK/128, KSPLIT);     // (1,64,8)
    mfma_gemm<3><<<grid,256,0,stream>>>(D_INNER/KSPLIT,
        u_bf, D_INNER, x_projT, D_INNER, pkpart, DBC_N, nullptr, nullptr);
    reduce_pk<<<(NTOK*(size_t)DBC_N)/1024,256,0,stream>>>(pkpart, dbc, dtbf);
  }
  // 4) delta = softplus(dtbf @ dt_proj_w + b)  (MFMA, K=64) -> bf16
  {
    dim3 grid(D_INNER/128, NTOK/128);
    mfma_gemm<4><<<grid,256,0,stream>>>(DT_RANK,
        dtbf, DT_RANK, dt_projT, DT_RANK, delta_bf, D_INNER, nullptr, dt_proj_b);
  }
  // 5) chunked scan (NC=32); part2 writes y bf16 in-place over z
  //    (qbuf overlays dead xi_bf)
  {
    dim3 grid1((D_INNER/256)*NC*BATCH);           // 1024 blocks
    scan_part1<<<grid1,256,0,stream>>>(dbc, delta_bf, u_bf, A_log, qbuf, sumdl);
    scan_combine<<<(BATCH*(size_t)D_INNER*D_STATE)/256,256,0,stream>>>(qbuf, sumdl, A_log);
    scan_part2<<<grid1,256,0,stream>>>(dbc, delta_bf, u_bf, zybuf, qbuf, A_log, Dp);
  }
  // 6) preln = y @ out_proj_w              (MFMA, f32 out)
  {
    dim3 grid(D_MODEL/128, NTOK/128);
    mfma_gemm<0><<<grid,256,0,stream>>>(D_INNER,
        zybuf, D_INNER, w_outT, D_INNER, preln, D_MODEL, nullptr, nullptr);
  }
  // 7) LayerNorm: preln f32 -> out f32
  ln_kernel<<<NTOK,256,0,stream>>>(preln, out, ln_gamma, ln_beta);
}

// Round 5
// 562.171 us; speedup vs baseline: 1.3378x; 1.0472x over previous
//
#include <hip/hip_runtime.h>
#include <math.h>

#define D_MODEL 1024
#define D_STATE 32
#define D_CONV  4
#define D_INNER 2048
#define DT_RANK 64
#define BATCH   4
#define SEQ     2048
#define NTOK    (BATCH*SEQ)            // 8192 rows
#define DBC_N   (DT_RANK + 2*D_STATE)  // 128
#define NC      32                     // scan chunks
#define CL      (SEQ/NC)               // 64 steps per chunk
#define KSPLIT  4                      // split-K factor for dbc GEMM
#define LOG2E   1.4426950408889634f

typedef unsigned short u16;
typedef short bf16x8 __attribute__((ext_vector_type(8)));
typedef float f32x4  __attribute__((ext_vector_type(4)));
typedef u16   u16x8  __attribute__((ext_vector_type(8)));

__device__ __forceinline__ float bf2f(u16 u){
  return __uint_as_float(((unsigned)u) << 16);
}
__device__ __forceinline__ u16 f2bf(float f){   // round-to-nearest-even
  unsigned u = __float_as_uint(f);
  return (u16)((u + 0x7fffu + ((u >> 16) & 1u)) >> 16);
}
__device__ __forceinline__ float sigmoidf_(float x){ return 1.f/(1.f+__expf(-x)); }
// raw v_exp_f32: r = 2^x (1 instruction; __expf = mul + this)
__device__ __forceinline__ float exp2_fast(float x){
  float r;
  asm("v_exp_f32 %0, %1" : "=v"(r) : "v"(x));
  return r;
}

typedef __attribute__((address_space(3))) void       lds_v;
typedef const __attribute__((address_space(1))) void gl_v;
#define GLOAD_LDS16(g, l) \
  __builtin_amdgcn_global_load_lds((gl_v*)(g), (lds_v*)(l), 16, 0, 0)

// ---------------------------------------------------------------------------
// bf16 MFMA GEMM: C = A[M,K] @ W[K,N], A bf16 row-major [M][K], B = weight
// PRE-TRANSPOSED bf16 [N][K]. 128x128 tile, BK=64, 4 waves of 64x64.
// Staging via global_load_lds width=16 into LINEAR [128][64] LDS (32 KB
// total). Row stride = 128 B -> naive reads are 16-way bank conflicts, so:
// SWIZZLE (both-sides-or-neither, rule #21): LDS[r][c'] holds logical 16B
// chunk c = c' ^ (r&7). Staging thread for dest chunk c_d of row r fetches
// global chunk c_d ^ (r&7) (coalescing preserved: full 128B rows, permuted
// within row). Reads XOR the same key -> all 8 bank-quads hit 2x per
// 16-lane group (2-way aliasing = free).
// MODES:
//  0: f32 store C1[row*ldc+col]                       (out_proj)
//  2: split in_proj, BOTH bf16: col<D_INNER -> (u16*)C1; else C2@col-2048
//  3: split-K partials: K arg = Kc; A,B advanced by kz*Kc;
//     store f32 at C1 + kz*NTOK*DBC_N                  (dbc)
//  4: softplus(acc + bias[col]) -> bf16 C1             (delta)
// ---------------------------------------------------------------------------
template<int MODE>
__global__ __launch_bounds__(256)
void mfma_gemm(int K,
               const u16* __restrict__ A, int lda,
               const u16* __restrict__ B, int ldb,   // [N][K]
               void* __restrict__ C1, int ldc,
               u16*  __restrict__ C2,
               const float* __restrict__ bias)
{
  __shared__ u16 As[128*64];
  __shared__ u16 Bs[128*64];
  const int tid  = threadIdx.x;
  const int lane = tid & 63;
  const int wave = tid >> 6;
  const int wm = (wave>>1)*64, wn = (wave&1)*64;
  const int m0 = blockIdx.y*128, n0 = blockIdx.x*128;
  const size_t koff = (MODE==3) ? (size_t)blockIdx.z*K : 0;

  // staging: 4 gloads/tile; gload g covers rows 32g..32g+31.
  const int srow = tid >> 3;            // 0..31 row within 32-row group
  const int sch  = ((tid & 7) ^ (srow & 7)) * 8;   // swizzled source chunk

  const u16* Ag = A + (size_t)(m0 + srow)*lda + sch + koff;
  const u16* Bg = B + (size_t)(n0 + srow)*ldb + sch + koff;

  const int fr = lane & 15;         // fragment row within 16
  const int fq = lane >> 4;         // quad: k-chunk of 8
  const int rkey = (fr & 7);        // read-side XOR key (loop-invariant)
  f32x4 acc[4][4] = {};

  for (int k0=0; k0<K; k0+=64){
    #pragma unroll
    for (int g=0; g<4; ++g){
      GLOAD_LDS16(Ag + (size_t)(32*g)*lda + k0, &As[g*2048 + tid*8]);
      GLOAD_LDS16(Bg + (size_t)(32*g)*ldb + k0, &Bs[g*2048 + tid*8]);
    }
    __syncthreads();                 // drains vmcnt -> LDS tile ready

    #pragma unroll
    for (int ks=0; ks<2; ++ks){
      const int rc = ((ks*4 + fq) ^ rkey) * 8;   // swizzled read chunk
      bf16x8 af[4], bfr[4];
      #pragma unroll
      for (int i=0;i<4;i++){
        af[i]  = *(const bf16x8*)&As[(wm + i*16 + fr)*64 + rc];
        bfr[i] = *(const bf16x8*)&Bs[(wn + i*16 + fr)*64 + rc];
      }
      #pragma unroll
      for (int mi=0;mi<4;mi++)
        #pragma unroll
        for (int ni=0;ni<4;ni++)
          acc[mi][ni] = __builtin_amdgcn_mfma_f32_16x16x32_bf16(
              af[mi], bfr[ni], acc[mi][ni], 0, 0, 0);
    }
    __syncthreads();                 // all reads done before next overwrite
  }

  float* Cf = (float*)C1;
  if (MODE==3) Cf += (size_t)blockIdx.z*((size_t)NTOK*DBC_N);

  // C/D layout: row = fq*4 + r, col = fr  (m89-verified)
  const bool second = (MODE==2) && (n0 >= D_INNER);   // block-uniform
  #pragma unroll
  for (int mi=0;mi<4;mi++){
    #pragma unroll
    for (int ni=0;ni<4;ni++){
      int col = n0 + wn + ni*16 + fr;
      #pragma unroll
      for (int r=0;r<4;r++){
        int row = m0 + wm + mi*16 + fq*4 + r;
        float v = acc[mi][ni][r];
        if (MODE==0 || MODE==3){
          Cf[(size_t)row*ldc + col] = v;
        } else if (MODE==4){
          v += bias[col];
          v = (v > 20.f) ? v : log1pf(__expf(v));
          ((u16*)C1)[(size_t)row*ldc + col] = f2bf(v);
        } else {  // MODE 2: dual bf16
          if (second) C2[(size_t)row*D_INNER + (col - D_INNER)] = f2bf(v);
          else        ((u16*)C1)[(size_t)row*D_INNER + col]     = f2bf(v);
        }
      }
    }
  }
}

// ---------------------------------------------------------------------------
// f32 -> bf16 elementwise (n multiple of 1024)
// ---------------------------------------------------------------------------
__global__ __launch_bounds__(256)
void cvt_f32_bf16(const float* __restrict__ in, u16* __restrict__ out)
{
  size_t i = (size_t)blockIdx.x*256 + threadIdx.x;
  float4 v = ((const float4*)in)[i];
  ushort4 o;
  o.x=f2bf(v.x); o.y=f2bf(v.y); o.z=f2bf(v.z); o.w=f2bf(v.w);
  ((ushort4*)out)[i] = o;
}

// ---------------------------------------------------------------------------
// f32 [R][C] -> bf16 [C][R] transpose+convert, 64x64 tiles, 256 threads.
// ---------------------------------------------------------------------------
__global__ __launch_bounds__(256)
void transpose_cvt(const float* __restrict__ in, u16* __restrict__ out,
                   int R, int C)
{
  __shared__ float tile[64][65];
  const int bc = blockIdx.x*64, br = blockIdx.y*64;
  const int tx = threadIdx.x & 63, ty = threadIdx.x >> 6;
  #pragma unroll
  for (int i=0;i<16;i++){
    int r = ty + i*4;
    tile[r][tx] = in[(size_t)(br+r)*C + bc+tx];
  }
  __syncthreads();
  #pragma unroll
  for (int i=0;i<16;i++){
    int r = ty + i*4;
    out[(size_t)(bc+r)*R + br+tx] = f2bf(tile[tx][r]);
  }
}

// ---------------------------------------------------------------------------
// reduce KSPLIT partials into dbc (float4-vectorized over NTOK*DBC_N).
// Also emits the dt columns (col<64) as bf16 [NTOK][64] for the delta MFMA.
// ---------------------------------------------------------------------------
__global__ __launch_bounds__(256)
void reduce_pk(const float* __restrict__ part, float* __restrict__ dbc,
               u16* __restrict__ dtbf)
{
  size_t i = (size_t)blockIdx.x*256 + threadIdx.x;   // float4 index
  const size_t stride4 = (size_t)NTOK*DBC_N/4;
  float4 s = ((const float4*)part)[i];
  #pragma unroll
  for (int z=1; z<KSPLIT; ++z){
    float4 v = ((const float4*)part)[z*stride4 + i];
    s.x+=v.x; s.y+=v.y; s.z+=v.z; s.w+=v.w;
  }
  ((float4*)dbc)[i] = s;
  int j = (int)(i & 31);               // float4 index within a 128-col row
  if (j < 16){                          // cols 0..63 = dt
    size_t row = i >> 5;
    ushort4 o;
    o.x=f2bf(s.x); o.y=f2bf(s.y); o.z=f2bf(s.z); o.w=f2bf(s.w);
    *(ushort4*)(dtbf + row*DT_RANK + 4*j) = o;
  }
}

// ---------------------------------------------------------------------------
// Depthwise causal conv (K=4) + bias + SiLU. bf16 in -> bf16 out (u).
// Vectorized: each thread handles 8 consecutive channels (ushort8 loads).
// ---------------------------------------------------------------------------
__global__ __launch_bounds__(256)
void conv_silu_kernel(const u16* __restrict__ xi_bf,
                      const float* __restrict__ conv_w,
                      const float* __restrict__ conv_b,
                      u16* __restrict__ u_bf)
{
  size_t i8 = (size_t)blockIdx.x*256 + threadIdx.x;  // over NTOK*D_INNER/8
  size_t base = i8*8;
  int d0 = (int)(base % D_INNER);
  size_t bt = base / D_INNER;
  int t = (int)(bt % SEQ);
  size_t b = bt / SEQ;
  const u16* xi = xi_bf + b*(size_t)SEQ*D_INNER + d0;

  float accv[8];
  #pragma unroll
  for (int j=0;j<8;j++) accv[j] = conv_b[d0+j];
  float4 cw[8];
  #pragma unroll
  for (int j=0;j<8;j++) cw[j] = *(const float4*)(conv_w + (size_t)(d0+j)*D_CONV);

  #pragma unroll
  for (int k=0;k<D_CONV;k++){
    int tt = t + k - (D_CONV-1);
    if (tt >= 0){
      u16x8 v = *(const u16x8*)(xi + (size_t)tt*D_INNER);
      const float* w = (const float*)&cw[0];
      accv[0] += bf2f(v[0]) * ((const float*)&cw[0])[k];
      accv[1] += bf2f(v[1]) * ((const float*)&cw[1])[k];
      accv[2] += bf2f(v[2]) * ((const float*)&cw[2])[k];
      accv[3] += bf2f(v[3]) * ((const float*)&cw[3])[k];
      accv[4] += bf2f(v[4]) * ((const float*)&cw[4])[k];
      accv[5] += bf2f(v[5]) * ((const float*)&cw[5])[k];
      accv[6] += bf2f(v[6]) * ((const float*)&cw[6])[k];
      accv[7] += bf2f(v[7]) * ((const float*)&cw[7])[k];
      (void)w;
    }
  }
  u16x8 o;
  #pragma unroll
  for (int j=0;j<8;j++){
    float r = accv[j] * sigmoidf_(accv[j]);
    o[j] = f2bf(r);
  }
  *(u16x8*)(u_bf + base) = o;
}

// ---------------------------------------------------------------------------
// Chunked selective scan, pass 1: lane = channel, h[32] in registers.
// FAST PATH (runtime-verified): A_log = log(tile(arange(1..32))) ->
// A2[s] = A2[0]*(s+1), so exp(dl*A[s]) = E^(s+1): ONE v_exp per timestep.
// delta/u are bf16.
// ---------------------------------------------------------------------------
__global__ __launch_bounds__(256)
void scan_part1(const float* __restrict__ dbc,     // (NTOK,128)
                const u16*   __restrict__ delta,   // (NTOK,D_INNER) bf16
                const u16*   __restrict__ u,       // (NTOK,D_INNER) bf16
                const float* __restrict__ A_log,   // (D_INNER,32)
                float* __restrict__ q,             // (B,NC,D_INNER,32)
                float* __restrict__ sumdl_buf)     // (B,NC,D_INNER)
{
  const int ndg  = D_INNER/256;                 // 8
  const int dgrp = blockIdx.x % ndg;
  const int c    = (blockIdx.x / ndg) % NC;
  const int b    =  blockIdx.x / (ndg*NC);
  const int d    = dgrp*256 + threadIdx.x;

  const float* Ap = A_log + (size_t)d*D_STATE;
  const float base = -__expf(Ap[0]) * LOG2E;      // log2e folded into A
  bool fastp = true;
  #pragma unroll
  for (int s=1; s<D_STATE; ++s){
    float a2 = -__expf(Ap[s]) * LOG2E;
    float ideal = base * (float)(s+1);
    fastp = fastp && (fabsf(a2 - ideal) <= 1e-4f*fabsf(ideal));
  }

  const size_t tok0 = (size_t)b*SEQ + (size_t)c*CL;
  const u16*   dptr = delta + tok0*D_INNER + d;
  const u16*   uptr = u     + tok0*D_INNER + d;
  const float* dbcp = dbc   + tok0*DBC_N;

  float h[D_STATE] = {};
  float sumdl = 0.f;

  if (fastp){
    for (int t=0; t<CL; ++t){
      float dl = bf2f(dptr[(size_t)t*D_INNER]);
      float uu = bf2f(uptr[(size_t)t*D_INNER]);
      sumdl += dl;
      float w  = dl*uu;
      float E  = exp2_fast(dl*base);
      float E2 = E*E, E3 = E2*E, E4 = E2*E2;
      float P  = 1.f;
      const float4* B4 = (const float4*)(dbcp + (size_t)t*DBC_N + DT_RANK);
      #pragma unroll
      for (int g=0; g<8; ++g){
        float4 Bv = B4[g];
        float m0 = P*E, m1 = P*E2, m2 = P*E3, m3 = P*E4;
        h[4*g+0] = m0*h[4*g+0] + w*Bv.x;
        h[4*g+1] = m1*h[4*g+1] + w*Bv.y;
        h[4*g+2] = m2*h[4*g+2] + w*Bv.z;
        h[4*g+3] = m3*h[4*g+3] + w*Bv.w;
        P = m3;
      }
    }
  } else {
    float A2[D_STATE];
    #pragma unroll
    for (int g=0; g<8; ++g){
      float4 al = *(const float4*)(Ap + 4*g);
      A2[4*g+0] = -__expf(al.x)*LOG2E; A2[4*g+1] = -__expf(al.y)*LOG2E;
      A2[4*g+2] = -__expf(al.z)*LOG2E; A2[4*g+3] = -__expf(al.w)*LOG2E;
    }
    for (int t=0; t<CL; ++t){
      float dl = bf2f(dptr[(size_t)t*D_INNER]);
      float uu = bf2f(uptr[(size_t)t*D_INNER]);
      sumdl += dl;
      float w = dl*uu;
      const float4* B4 = (const float4*)(dbcp + (size_t)t*DBC_N + DT_RANK);
      #pragma unroll
      for (int g=0; g<8; ++g){
        float4 Bv = B4[g];
        h[4*g+0] = exp2_fast(dl*A2[4*g+0])*h[4*g+0] + w*Bv.x;
        h[4*g+1] = exp2_fast(dl*A2[4*g+1])*h[4*g+1] + w*Bv.y;
        h[4*g+2] = exp2_fast(dl*A2[4*g+2])*h[4*g+2] + w*Bv.z;
        h[4*g+3] = exp2_fast(dl*A2[4*g+3])*h[4*g+3] + w*Bv.w;
      }
    }
  }

  float* qp = q + (((size_t)b*NC + c)*D_INNER + d)*D_STATE;
  #pragma unroll
  for (int g=0; g<8; ++g)
    ((float4*)qp)[g] = make_float4(h[4*g+0],h[4*g+1],h[4*g+2],h[4*g+3]);
  sumdl_buf[((size_t)b*NC + c)*D_INNER + d] = sumdl;
}

// ---------------------------------------------------------------------------
// Pass 2: sequential combine across chunks, in-place on q.
// ---------------------------------------------------------------------------
__global__ __launch_bounds__(256)
void scan_combine(float* __restrict__ q,
                  const float* __restrict__ sumdl_buf,
                  const float* __restrict__ A_log)
{
  size_t idx = (size_t)blockIdx.x*256 + threadIdx.x;   // over B*D_INNER*32
  int s = (int)(idx % D_STATE);
  size_t dd = idx / D_STATE;
  int d = (int)(dd % D_INNER);
  int b = (int)(dd / D_INNER);

  const float As2 = -__expf(A_log[(size_t)d*D_STATE + s]) * LOG2E;
  float H = 0.f;
  for (int c=0; c<NC; ++c){
    size_t off = (((size_t)b*NC + c)*D_INNER + d)*D_STATE + s;
    float tmp = q[off];          // chunk-local end state
    q[off] = H;                  // h_in for chunk c
    H = exp2_fast(As2 * sumdl_buf[((size_t)b*NC + c)*D_INNER + d]) * H + tmp;
  }
}

// ---------------------------------------------------------------------------
// Pass 3: re-run recurrence from h_in; y = sum_s h*C, fused D-skip + z-gate.
// z bf16 read, y bf16 written IN-PLACE (same slot, same thread -> race-free).
// delta/u are bf16.
// ---------------------------------------------------------------------------
__global__ __launch_bounds__(256)
void scan_part2(const float* __restrict__ dbc,     // (NTOK,128)
                const u16*   __restrict__ delta,   // (NTOK,D_INNER) bf16
                const u16*   __restrict__ u,       // bf16
                u16*         __restrict__ zy,      // in: z bf16, out: y bf16
                const float* __restrict__ q,       // h_in per chunk
                const float* __restrict__ A_log,
                const float* __restrict__ Dp)
{
  const int ndg  = D_INNER/256;
  const int dgrp = blockIdx.x % ndg;
  const int c    = (blockIdx.x / ndg) % NC;
  const int b    =  blockIdx.x / (ndg*NC);
  const int d    = dgrp*256 + threadIdx.x;

  const float* Ap = A_log + (size_t)d*D_STATE;
  const float base = -__expf(Ap[0]) * LOG2E;
  bool fastp = true;
  #pragma unroll
  for (int s=1; s<D_STATE; ++s){
    float a2 = -__expf(Ap[s]) * LOG2E;
    float ideal = base * (float)(s+1);
    fastp = fastp && (fabsf(a2 - ideal) <= 1e-4f*fabsf(ideal));
  }

  float h[D_STATE];
  const float* qp = q + (((size_t)b*NC + c)*D_INNER + d)*D_STATE;
  #pragma unroll
  for (int g=0; g<8; ++g){
    float4 hv = ((const float4*)qp)[g];
    h[4*g+0]=hv.x; h[4*g+1]=hv.y; h[4*g+2]=hv.z; h[4*g+3]=hv.w;
  }
  const float Dd = Dp[d];

  const size_t tok0 = (size_t)b*SEQ + (size_t)c*CL;
  const u16*   dptr = delta + tok0*D_INNER + d;
  const u16*   uptr = u     + tok0*D_INNER + d;
  u16*         zp   = zy    + tok0*D_INNER + d;
  const float* dbcp = dbc   + tok0*DBC_N;

  if (fastp){
    for (int t=0; t<CL; ++t){
      float dl = bf2f(dptr[(size_t)t*D_INNER]);
      float uu = bf2f(uptr[(size_t)t*D_INNER]);
      float zz = bf2f(zp[(size_t)t*D_INNER]);
      float w  = dl*uu;
      float E  = exp2_fast(dl*base);
      float E2 = E*E, E3 = E2*E, E4 = E2*E2;
      float P  = 1.f;
      const float4* B4 = (const float4*)(dbcp + (size_t)t*DBC_N + DT_RANK);
      const float4* C4 = B4 + 8;
      float y = 0.f;
      #pragma unroll
      for (int g=0; g<8; ++g){
        float4 Bv = B4[g];
        float4 Cv = C4[g];
        float m0 = P*E, m1 = P*E2, m2 = P*E3, m3 = P*E4;
        h[4*g+0] = m0*h[4*g+0] + w*Bv.x;  y += h[4*g+0]*Cv.x;
        h[4*g+1] = m1*h[4*g+1] + w*Bv.y;  y += h[4*g+1]*Cv.y;
        h[4*g+2] = m2*h[4*g+2] + w*Bv.z;  y += h[4*g+2]*Cv.z;
        h[4*g+3] = m3*h[4*g+3] + w*Bv.w;  y += h[4*g+3]*Cv.w;
        P = m3;
      }
      zp[(size_t)t*D_INNER] = f2bf((y + uu*Dd) * (zz * sigmoidf_(zz)));
    }
  } else {
    float A2[D_STATE];
    #pragma unroll
    for (int g=0; g<8; ++g){
      float4 al = *(const float4*)(Ap + 4*g);
      A2[4*g+0] = -__expf(al.x)*LOG2E; A2[4*g+1] = -__expf(al.y)*LOG2E;
      A2[4*g+2] = -__expf(al.z)*LOG2E; A2[4*g+3] = -__expf(al.w)*LOG2E;
    }
    for (int t=0; t<CL; ++t){
      float dl = bf2f(dptr[(size_t)t*D_INNER]);
      float uu = bf2f(uptr[(size_t)t*D_INNER]);
      float zz = bf2f(zp[(size_t)t*D_INNER]);
      float w  = dl*uu;
      const float4* B4 = (const float4*)(dbcp + (size_t)t*DBC_N + DT_RANK);
      const float4* C4 = B4 + 8;
      float y = 0.f;
      #pragma unroll
      for (int g=0; g<8; ++g){
        float4 Bv = B4[g];
        float4 Cv = C4[g];
        h[4*g+0] = exp2_fast(dl*A2[4*g+0])*h[4*g+0] + w*Bv.x;  y += h[4*g+0]*Cv.x;
        h[4*g+1] = exp2_fast(dl*A2[4*g+1])*h[4*g+1] + w*Bv.y;  y += h[4*g+1]*Cv.y;
        h[4*g+2] = exp2_fast(dl*A2[4*g+2])*h[4*g+2] + w*Bv.z;  y += h[4*g+2]*Cv.z;
        h[4*g+3] = exp2_fast(dl*A2[4*g+3])*h[4*g+3] + w*Bv.w;  y += h[4*g+3]*Cv.w;
      }
      zp[(size_t)t*D_INNER] = f2bf((y + uu*Dd) * (zz * sigmoidf_(zz)));
    }
  }
}

// ---------------------------------------------------------------------------
// LayerNorm over last dim (1024): read f32 pre-LN, write f32 output.
// float4 loads/stores: thread t owns cols [4t, 4t+4).
// ---------------------------------------------------------------------------
__global__ __launch_bounds__(256)
void ln_kernel(const float* __restrict__ in,
               float* __restrict__ out,
               const float* __restrict__ gamma,
               const float* __restrict__ beta)
{
  const int row = blockIdx.x;
  const float* p = in + (size_t)row*D_MODEL;
  float* q = out + (size_t)row*D_MODEL;
  float4 v = ((const float4*)p)[threadIdx.x];
  float s  = v.x+v.y+v.z+v.w;
  float ss = v.x*v.x+v.y*v.y+v.z*v.z+v.w*v.w;
  #pragma unroll
  for (int off=32; off; off>>=1){
    s  += __shfl_xor(s,  off, 64);
    ss += __shfl_xor(ss, off, 64);
  }
  __shared__ float sw[4], ssw[4];
  const int wid = threadIdx.x >> 6;
  if ((threadIdx.x & 63) == 0){ sw[wid]=s; ssw[wid]=ss; }
  __syncthreads();
  s  = sw[0]+sw[1]+sw[2]+sw[3];
  ss = ssw[0]+ssw[1]+ssw[2]+ssw[3];
  const float mu  = s * (1.f/D_MODEL);
  const float var = ss * (1.f/D_MODEL) - mu*mu;
  const float inv = rsqrtf(var + 1e-5f);
  float4 gm = ((const float4*)gamma)[threadIdx.x];
  float4 bt = ((const float4*)beta )[threadIdx.x];
  float4 o;
  o.x = (v.x-mu)*inv*gm.x + bt.x;
  o.y = (v.y-mu)*inv*gm.y + bt.y;
  o.z = (v.z-mu)*inv*gm.z + bt.z;
  o.w = (v.w-mu)*inv*gm.w + bt.w;
  ((float4*)q)[threadIdx.x] = o;
}

// ---------------------------------------------------------------------------
extern "C" void kernel_launch(void* const* d_in, const int* in_sizes, int n_in,
                              void* d_out, int out_size, void* d_ws, size_t ws_size,
                              hipStream_t stream)
{
  const float* x          = (const float*)d_in[0];   // (4,2048,1024) f32
  const float* in_proj_w  = (const float*)d_in[1];   // (1024,4096)
  const float* conv_w     = (const float*)d_in[2];   // (2048,4)
  const float* conv_b     = (const float*)d_in[3];   // (2048,)
  const float* x_proj_w   = (const float*)d_in[4];   // (2048,128)
  const float* dt_proj_w  = (const float*)d_in[5];   // (64,2048)
  const float* dt_proj_b  = (const float*)d_in[6];   // (2048,)
  const float* A_log      = (const float*)d_in[7];   // (2048,32)
  const float* Dp         = (const float*)d_in[8];   // (2048,)
  const float* out_proj_w = (const float*)d_in[9];   // (2048,1024)
  const float* ln_gamma   = (const float*)d_in[10];  // (1024,)
  const float* ln_beta    = (const float*)d_in[11];  // (1024,)
  float* out = (float*)d_out;                        // (4,2048,1024) f32 OUTPUT

  // workspace (byte offsets), ws_size = 256 MiB:
  //   @0    x_bf bf16 16M (steps 0-1) -> pkpart f32 16M (step 3)
  //   @32M  xi_bf bf16 32M (steps 1-2) -> qbuf f32 32M (step 5)
  //   @64M  u_bf bf16 32M (steps 2,3,5)
  //   @96M  zybuf bf16 32M (steps 1,5,6)
  //   @128M delta_bf bf16 32M (steps 4,5)
  //   @160M dbc f32 4M ; @164M dtbf 1M ; @165M sumdl 1M
  //   @166M preln f32 32M (steps 6,7)
  //   @198M w_inT 8M ; @206M w_outT 4M ; @210M x_projT .5M ; @210.5M dt_projT
  char* ws = (char*)d_ws;
  u16*   x_bf    = (u16*)  (ws + 0);
  float* pkpart  = (float*)(ws + 0);
  u16*   xi_bf   = (u16*)  (ws + (size_t) 33554432);
  float* qbuf    = (float*)(ws + (size_t) 33554432);
  u16*   u_bf    = (u16*)  (ws + (size_t) 67108864);
  u16*   zybuf   = (u16*)  (ws + (size_t)100663296);
  u16*   delta_bf= (u16*)  (ws + (size_t)134217728);
  float* dbc     = (float*)(ws + (size_t)167772160);
  u16*   dtbf    = (u16*)  (ws + (size_t)171966464);
  float* sumdl   = (float*)(ws + (size_t)173015040);
  float* preln   = (float*)(ws + (size_t)174063616);
  u16*   w_inT   = (u16*)  (ws + (size_t)207618048);
  u16*   w_outT  = (u16*)  (ws + (size_t)216006656);
  u16*   x_projT = (u16*)  (ws + (size_t)220200960);
  u16*   dt_projT= (u16*)  (ws + (size_t)220725248);

  // 0) dtype prep: x -> bf16; weights -> bf16 transposed [N][K]
  cvt_f32_bf16<<<(NTOK*(size_t)D_MODEL)/1024, 256, 0, stream>>>(x, x_bf);
  { dim3 g(4096/64, 1024/64); transpose_cvt<<<g,256,0,stream>>>(in_proj_w,  w_inT,  1024, 4096); }
  { dim3 g(1024/64, 2048/64); transpose_cvt<<<g,256,0,stream>>>(out_proj_w, w_outT, 2048, 1024); }
  { dim3 g( 128/64, 2048/64); transpose_cvt<<<g,256,0,stream>>>(x_proj_w,   x_projT, 2048, 128); }
  { dim3 g(2048/64,   64/64); transpose_cvt<<<g,256,0,stream>>>(dt_proj_w,  dt_projT,  64, 2048); }

  // 1) merged in_proj: [xi | z] = x @ in_proj_w  (MFMA, dual bf16 epilogue)
  {
    dim3 grid(2*D_INNER/128, NTOK/128);
    mfma_gemm<2><<<grid,256,0,stream>>>(D_MODEL,
        x_bf, D_MODEL, w_inT, D_MODEL, xi_bf, 0, zybuf, nullptr);
  }
  // 2) u = silu(conv(xi) + conv_b)   bf16 -> bf16  (xi_bf dead after)
  conv_silu_kernel<<<(NTOK*(size_t)D_INNER)/2048,256,0,stream>>>(
      xi_bf, conv_w, conv_b, u_bf);

  // 3) dbc = u_bf @ x_proj_w  (MFMA split-K over 4, partials @0, x_bf dead).
  //    reduce also emits dt cols as bf16 for step 4.
  {
    dim3 grid(DBC_N/128, NTOK/128, KSPLIT);     // (1,64,4)
    mfma_gemm<3><<<grid,256,0,stream>>>(D_INNER/KSPLIT,
        u_bf, D_INNER, x_projT, D_INNER, pkpart, DBC_N, nullptr, nullptr);
    reduce_pk<<<(NTOK*(size_t)DBC_N)/1024,256,0,stream>>>(pkpart, dbc, dtbf);
  }
  // 4) delta = softplus(dtbf @ dt_proj_w + b)  (MFMA, K=64) -> bf16
  {
    dim3 grid(D_INNER/128, NTOK/128);
    mfma_gemm<4><<<grid,256,0,stream>>>(DT_RANK,
        dtbf, DT_RANK, dt_projT, DT_RANK, delta_bf, D_INNER, nullptr, dt_proj_b);
  }
  // 5) chunked scan (NC=32); part2 writes y bf16 in-place over z
  //    (qbuf overlays dead xi_bf)
  {
    dim3 grid1((D_INNER/256)*NC*BATCH);           // 1024 blocks
    scan_part1<<<grid1,256,0,stream>>>(dbc, delta_bf, u_bf, A_log, qbuf, sumdl);
    scan_combine<<<(BATCH*(size_t)D_INNER*D_STATE)/256,256,0,stream>>>(qbuf, sumdl, A_log);
    scan_part2<<<grid1,256,0,stream>>>(dbc, delta_bf, u_bf, zybuf, qbuf, A_log, Dp);
  }
  // 6) preln = y @ out_proj_w              (MFMA, f32 out)
  {
    dim3 grid(D_MODEL/128, NTOK/128);
    mfma_gemm<0><<<grid,256,0,stream>>>(D_INNER,
        zybuf, D_INNER, w_outT, D_INNER, preln, D_MODEL, nullptr, nullptr);
  }
  // 7) LayerNorm: preln f32 -> out f32
  ln_kernel<<<NTOK,256,0,stream>>>(preln, out, ln_gamma, ln_beta);
}